// Round 9
// baseline (300.115 us; speedup 1.0000x reference)
//
#include <hip/hip_runtime.h>

constexpr int Bn = 4;
constexpr int Hn = 64;
constexpr int Wn = 64;
constexpr int LL = Hn * Wn;     // 4096
constexpr int DM = 128;
constexpr int DI = 256;
constexpr int Nn = 16;
constexpr int Rn = 8;
constexpr int Kn = 4;
constexpr int NC = 128;         // chunks per (b,k) scan
constexpr int CHUNK = LL / NC;  // 32

using bf16x8 = __attribute__((ext_vector_type(8))) short;
using f32x4  = __attribute__((ext_vector_type(4))) float;

// ---------- helpers ----------
__device__ __forceinline__ float bf2f(unsigned short s) {
    return __uint_as_float(((unsigned int)s) << 16);
}
__device__ __forceinline__ unsigned short f2bf(float f) {
    unsigned int u = __float_as_uint(f);
    u += 0x7FFFu + ((u >> 16) & 1u);   // RNE
    return (unsigned short)(u >> 16);
}
__device__ __forceinline__ float softplus_f(float x) {
    if (x > 20.f) return x;
    return __logf(1.f + __expf(x));
}
// de = softplus(dtv), e1 = exp(-de) == 1/(1+exp(dtv))
__device__ __forceinline__ void softplus_e1(float dtv, float& de, float& e1) {
    float E = __expf(dtv);
    de = (dtv > 20.f) ? dtv : __logf(1.f + E);
    e1 = __builtin_amdgcn_rcpf(1.f + E);
}
// scan-order index t -> image position (row-major h*64+w)
__device__ __forceinline__ int posk(int k, int t) {
    int q = (k >= 2) ? (LL - 1 - t) : t;
    return (k & 1) ? (((q & 63) << 6) | (q >> 6)) : q;
}
__device__ __forceinline__ float dot8(const float wr[8], const float* __restrict__ rec) {
    float4 q0 = *(const float4*)rec;
    float4 q1 = *(const float4*)(rec + 4);
    return wr[0] * q0.x + wr[1] * q0.y + wr[2] * q0.z + wr[3] * q0.w
         + wr[4] * q1.x + wr[5] * q1.y + wr[6] * q1.z + wr[7] * q1.w;
}
__device__ __forceinline__ void load_wr(const float* __restrict__ dtw, int kd, float wr[8]) {
    float4 v0 = *(const float4*)(dtw + (size_t)kd * 8);
    float4 v1 = *(const float4*)(dtw + (size_t)kd * 8 + 4);
    wr[0] = v0.x; wr[1] = v0.y; wr[2] = v0.z; wr[3] = v0.w;
    wr[4] = v1.x; wr[5] = v1.y; wr[6] = v1.z; wr[7] = v1.w;
}
// e1^(n+1) for n=0..15, depth-4 tree
__device__ __forceinline__ void pow16(float e1, float en[16]) {
    float e2 = e1 * e1, e4 = e2 * e2, e8 = e4 * e4;
    en[0] = e1;        en[1] = e2;        en[2] = e2 * e1;   en[3] = e4;
    en[4] = e4 * e1;   en[5] = e4 * e2;   en[6] = en[5] * e1; en[7] = e8;
    en[8] = e8 * e1;   en[9] = e8 * e2;   en[10] = en[9] * e1; en[11] = e8 * e4;
    en[12] = en[11] * e1; en[13] = en[11] * e2; en[14] = en[13] * e1; en[15] = e8 * e8;
}
// true iff -exp(A_logs[kd][n]) == -(n+1)
__device__ __forceinline__ bool check_chain(const float* __restrict__ A_logs, int kd) {
    float a0 = -__expf(A_logs[(size_t)kd * 16]);
    bool ok = fabsf(a0 + 1.f) < 1e-6f;
    #pragma unroll
    for (int n = 1; n < 16; ++n) {
        float an = -__expf(A_logs[(size_t)kd * 16 + n]);
        ok = ok && (fabsf(an - (float)(n + 1) * a0) <= 1e-4f * fabsf(an));
    }
    return ok;
}

// ---------- kernel 1: in_proj GEMM via MFMA bf16 ----------
__global__ __launch_bounds__(256) void k_inproj(const float* __restrict__ x,
                                                const float* __restrict__ wp,
                                                float* __restrict__ out) {
    __shared__ short sA[64][40];
    __shared__ short sW[256][40];
    int r0 = blockIdx.x * 64;
    int tid = threadIdx.x;
    int w = tid >> 6, lane = tid & 63;
    int ln15 = lane & 15, q8 = (lane >> 4) * 8;
    f32x4 acc[16];
    #pragma unroll
    for (int i = 0; i < 16; ++i) acc[i] = f32x4{0.f, 0.f, 0.f, 0.f};
    for (int kk = 0; kk < 4; ++kk) {
        {
            int r = tid >> 2, c0 = (tid & 3) * 8;
            const float* src = x + (size_t)(r0 + r) * DM + kk * 32 + c0;
            float4 v0 = *(const float4*)src;
            float4 v1 = *(const float4*)(src + 4);
            bf16x8 s;
            s[0] = (short)f2bf(v0.x); s[1] = (short)f2bf(v0.y);
            s[2] = (short)f2bf(v0.z); s[3] = (short)f2bf(v0.w);
            s[4] = (short)f2bf(v1.x); s[5] = (short)f2bf(v1.y);
            s[6] = (short)f2bf(v1.z); s[7] = (short)f2bf(v1.w);
            *(bf16x8*)&sA[r][c0] = s;
        }
        {
            const float* src = wp + (size_t)tid * DM + kk * 32;
            #pragma unroll
            for (int j = 0; j < 8; ++j) {
                float4 v = *(const float4*)(src + j * 4);
                sW[tid][j * 4 + 0] = (short)f2bf(v.x);
                sW[tid][j * 4 + 1] = (short)f2bf(v.y);
                sW[tid][j * 4 + 2] = (short)f2bf(v.z);
                sW[tid][j * 4 + 3] = (short)f2bf(v.w);
            }
        }
        __syncthreads();
        bf16x8 a = *(bf16x8*)&sA[w * 16 + ln15][q8];
        #pragma unroll
        for (int ni = 0; ni < 16; ++ni) {
            bf16x8 bfr = *(bf16x8*)&sW[ni * 16 + ln15][q8];
            acc[ni] = __builtin_amdgcn_mfma_f32_16x16x32_bf16(a, bfr, acc[ni], 0, 0, 0);
        }
        __syncthreads();
    }
    int rbase = r0 + w * 16 + (lane >> 4) * 4;
    #pragma unroll
    for (int ni = 0; ni < 16; ++ni)
        #pragma unroll
        for (int r = 0; r < 4; ++r)
            out[(size_t)(rbase + r) * DI + ni * 16 + ln15] = acc[ni][r];
}

// ---------- kernel 2: depthwise 3x3 conv + bias + SiLU, channel-last; emits bf16 ----------
__global__ __launch_bounds__(256) void k_conv(const float* __restrict__ xin,
                                              const float* __restrict__ cw,
                                              const float* __restrict__ cb,
                                              unsigned short* __restrict__ xoutB) {
    int bid = blockIdx.x;
    int hh   = bid & 1;
    int wblk = (bid >> 1) & 15;
    int dblk = (bid >> 5) & 3;
    int b    = bid >> 7;
    int tid = threadIdx.x;
    int d = dblk * 64 + (tid & 63);
    int w = wblk * 4 + (tid >> 6);
    const float* inb = xin + (size_t)b * LL * DI + d;
    unsigned short* outbB = xoutB + (size_t)b * LL * DI + d;
    float wg[9];
    #pragma unroll
    for (int i = 0; i < 9; ++i) wg[i] = cw[d * 9 + i];
    float bias = cb[d];
    #define LDV(hhh, www) ((((www) >= 0) && ((www) < Wn)) ? inb[(size_t)((hhh) * Wn + (www)) * DI] : 0.f)
    int hs = hh * 32;
    float r0[3], r1[3], r2[3];
    if (hs == 0) { r0[0] = r0[1] = r0[2] = 0.f; }
    else { r0[0] = LDV(hs - 1, w - 1); r0[1] = LDV(hs - 1, w); r0[2] = LDV(hs - 1, w + 1); }
    r1[0] = LDV(hs, w - 1); r1[1] = LDV(hs, w); r1[2] = LDV(hs, w + 1);
    r2[0] = LDV(hs + 1, w - 1); r2[1] = LDV(hs + 1, w); r2[2] = LDV(hs + 1, w + 1);
    for (int h = hs; h < hs + 32; ++h) {
        float acc = bias + wg[0] * r0[0] + wg[1] * r0[1] + wg[2] * r0[2]
                         + wg[3] * r1[0] + wg[4] * r1[1] + wg[5] * r1[2]
                         + wg[6] * r2[0] + wg[7] * r2[1] + wg[8] * r2[2];
        float sig = 1.f / (1.f + __expf(-acc));
        outbB[(size_t)(h * Wn + w) * DI] = f2bf(acc * sig);
        r0[0] = r1[0]; r0[1] = r1[1]; r0[2] = r1[2];
        r1[0] = r2[0]; r1[1] = r2[1]; r1[2] = r2[2];
        if (h + 2 < Hn) { r2[0] = LDV(h + 2, w - 1); r2[1] = LDV(h + 2, w); r2[2] = LDV(h + 2, w + 1); }
        else { r2[0] = r2[1] = r2[2] = 0.f; }
    }
    #undef LDV
}

// ---------- kernel 3: projection GEMM via MFMA bf16 ----------
__global__ __launch_bounds__(256) void k_proj(const unsigned short* __restrict__ xcB,
                                              const float* __restrict__ xpw,
                                              float* __restrict__ P) {
    __shared__ short sA[64][40];
    __shared__ short sW[160][40];
    int r0 = blockIdx.x * 64;
    int tid = threadIdx.x;
    int w = tid >> 6, lane = tid & 63;
    int ln15 = lane & 15, q8 = (lane >> 4) * 8;
    f32x4 acc[10];
    #pragma unroll
    for (int i = 0; i < 10; ++i) acc[i] = f32x4{0.f, 0.f, 0.f, 0.f};
    for (int kk = 0; kk < 8; ++kk) {
        {
            int r = tid >> 2, c0 = (tid & 3) * 8;
            *(bf16x8*)&sA[r][c0] =
                *(const bf16x8*)(xcB + (size_t)(r0 + r) * DI + kk * 32 + c0);
        }
        if (tid < 160) {
            const float* src = xpw + (size_t)tid * DI + kk * 32;
            #pragma unroll
            for (int j = 0; j < 8; ++j) {
                float4 v = *(const float4*)(src + j * 4);
                sW[tid][j * 4 + 0] = (short)f2bf(v.x);
                sW[tid][j * 4 + 1] = (short)f2bf(v.y);
                sW[tid][j * 4 + 2] = (short)f2bf(v.z);
                sW[tid][j * 4 + 3] = (short)f2bf(v.w);
            }
        }
        __syncthreads();
        bf16x8 a = *(bf16x8*)&sA[w * 16 + ln15][q8];
        #pragma unroll
        for (int ni = 0; ni < 10; ++ni) {
            bf16x8 bfr = *(bf16x8*)&sW[ni * 16 + ln15][q8];
            acc[ni] = __builtin_amdgcn_mfma_f32_16x16x32_bf16(a, bfr, acc[ni], 0, 0, 0);
        }
        __syncthreads();
    }
    int rbase = r0 + w * 16 + (lane >> 4) * 4;
    #pragma unroll
    for (int ni = 0; ni < 10; ++ni)
        #pragma unroll
        for (int r = 0; r < 4; ++r)
            P[(size_t)(rbase + r) * 160 + ni * 16 + ln15] = acc[ni][r];
}

// ---------- scan step cores (rec points into LDS) ----------
template <bool CHAIN>
__device__ __forceinline__ float s1_step(const float* rec, float u,
                                         const float wr[8], float bias, float Dv,
                                         const float* __restrict__ A_logs, int kd,
                                         float h[16], float& sde) {
    float dtv = bias + dot8(wr, rec);
    float de, e1;
    softplus_e1(dtv, de, e1);
    float du = de * u;
    sde += de;
    float Ba[16], Ca[16];
    #pragma unroll
    for (int i = 0; i < 4; ++i) {
        float4 v = *(const float4*)(rec + 8 + i * 4);
        Ba[i * 4 + 0] = v.x; Ba[i * 4 + 1] = v.y; Ba[i * 4 + 2] = v.z; Ba[i * 4 + 3] = v.w;
        float4 w = *(const float4*)(rec + 24 + i * 4);
        Ca[i * 4 + 0] = w.x; Ca[i * 4 + 1] = w.y; Ca[i * 4 + 2] = w.z; Ca[i * 4 + 3] = w.w;
    }
    float yv[4];
    yv[0] = Dv * u; yv[1] = 0.f; yv[2] = 0.f; yv[3] = 0.f;
    if constexpr (CHAIN) {
        float en[16];
        pow16(e1, en);
        #pragma unroll
        for (int n = 0; n < 16; ++n) {
            h[n] = en[n] * h[n] + du * Ba[n];
            yv[n & 3] += h[n] * Ca[n];
        }
    } else {
        #pragma unroll
        for (int n = 0; n < 16; ++n) {
            float Ac = -__expf(A_logs[(size_t)kd * 16 + n]);
            h[n] = __expf(de * Ac) * h[n] + du * Ba[n];
            yv[n & 3] += h[n] * Ca[n];
        }
    }
    return (yv[0] + yv[1]) + (yv[2] + yv[3]);
}
template <bool CHAIN>
__device__ __forceinline__ float s3_step(const float* rec,
                                         const float wr[8], float bias,
                                         const float* __restrict__ A_logs, int kd,
                                         float g[16], const float h0[16], float& sde) {
    float dtv = bias + dot8(wr, rec);
    float Ca[16];
    #pragma unroll
    for (int i = 0; i < 4; ++i) {
        float4 w = *(const float4*)(rec + 24 + i * 4);
        Ca[i * 4 + 0] = w.x; Ca[i * 4 + 1] = w.y; Ca[i * 4 + 2] = w.z; Ca[i * 4 + 3] = w.w;
    }
    float cv[4] = {0.f, 0.f, 0.f, 0.f};
    if constexpr (CHAIN) {
        float E = __expf(dtv);
        float e1 = __builtin_amdgcn_rcpf(1.f + E);
        float en[16];
        pow16(e1, en);
        #pragma unroll
        for (int n = 0; n < 16; ++n) {
            g[n] *= en[n];
            cv[n & 3] += g[n] * Ca[n];
        }
    } else {
        float de = softplus_f(dtv);
        sde += de;
        #pragma unroll
        for (int n = 0; n < 16; ++n) {
            float Ac = -__expf(A_logs[(size_t)kd * 16 + n]);
            cv[n & 3] += Ca[n] * __expf(Ac * sde) * h0[n];
        }
    }
    return (cv[0] + cv[1]) + (cv[2] + cv[3]);
}

// window geometry + cooperative staging of both directions' records into LDS
struct WinGeom { int pA0, dpA, pB0, dpB, kA, kB, c, cB, b; };
__device__ __forceinline__ WinGeom win_geom(int bid) {
    WinGeom g;
    g.c = bid & (NC - 1);
    int p = (bid >> 7) & 1;
    g.b = bid >> 8;
    g.kA = p; g.kB = p + 2; g.cB = NC - 1 - g.c;
    int t0A = g.c * CHUNK, t0B = g.cB * CHUNK;
    g.pA0 = posk(g.kA, t0A); g.dpA = posk(g.kA, t0A + 1) - g.pA0;
    g.pB0 = posk(g.kB, t0B); g.dpB = posk(g.kB, t0B + 1) - g.pB0;
    return g;
}
__device__ __forceinline__ void stage_recs(const float* __restrict__ P, const WinGeom& g,
                                           int tid, float (*sR)[CHUNK][44]) {
    const float* Pb = P + (size_t)g.b * LL * 160;
    long gA = (long)g.pA0 * 160 + g.kA * 40, stA = (long)g.dpA * 160;
    long gB = (long)g.pB0 * 160 + g.kB * 40, stB = (long)g.dpB * 160;
    for (int i = tid; i < 640; i += 256) {
        int dir = (i >= 320) ? 1 : 0;
        int r = i - dir * 320;
        int j = r / 10, q = r - j * 10;
        long off = (dir ? gB + (long)j * stB : gA + (long)j * stA) + q * 4;
        *(float4*)&sR[dir][j][q * 4] = *(const float4*)(Pb + off);
    }
    __syncthreads();
}

// ---------- kernel 4: paired local scan — LDS-staged records, interleaved dirs ----------
// grid 1024 = 4b * 2pair * 128c ; pair0 -> y0(=d_out), pair1 -> y1 (wh-scan layout)
__global__ __launch_bounds__(256) void k_scan1p(const unsigned short* __restrict__ xcB,
                                                const float* __restrict__ P,
                                                const float* __restrict__ dtw,
                                                const float* __restrict__ dtb,
                                                const float* __restrict__ A_logs,
                                                const float* __restrict__ Ds,
                                                float* __restrict__ carrG,
                                                unsigned short* __restrict__ carrH,
                                                float* __restrict__ y0,
                                                float* __restrict__ y1) {
    __shared__ float sR[2][CHUNK][44];
    int bid = blockIdx.x;
    int tid = threadIdx.x;
    WinGeom g = win_geom(bid);
    stage_recs(P, g, tid, sR);
    int kdA = g.kA * DI + tid, kdB = g.kB * DI + tid;
    float wrA[8], wrB[8];
    load_wr(dtw, kdA, wrA);
    load_wr(dtw, kdB, wrB);
    float biasA = dtb[kdA], biasB = dtb[kdB];
    float DvA = Ds[kdA], DvB = Ds[kdB];
    bool ch = check_chain(A_logs, kdA) && check_chain(A_logs, kdB);
    float hA[16], hB[16];
    #pragma unroll
    for (int n = 0; n < 16; ++n) { hA[n] = 0.f; hB[n] = 0.f; }
    float sdeA = 0.f, sdeB = 0.f;
    const unsigned short* upA = xcB + ((size_t)g.b * LL + g.pA0) * DI + tid;
    const unsigned short* upB = xcB + ((size_t)g.b * LL + g.pB0) * DI + tid;
    long usA = (long)g.dpA * DI, usB = (long)g.dpB * DI;
    int p = g.kA;
    float* yb = (p == 0 ? y0 : y1) + ((size_t)g.b * LL + g.c * CHUNK) * DI + tid;
    // first half: "=" stores (A owns slots 0..15, B owns 16..31)
    #pragma unroll 2
    for (int tt = 0; tt < CHUNK / 2; ++tt) {
        float yvA, yvB;
        if (ch) {
            yvA = s1_step<true>(&sR[0][tt][0], bf2f(*upA), wrA, biasA, DvA, A_logs, kdA, hA, sdeA);
            yvB = s1_step<true>(&sR[1][tt][0], bf2f(*upB), wrB, biasB, DvB, A_logs, kdB, hB, sdeB);
        } else {
            yvA = s1_step<false>(&sR[0][tt][0], bf2f(*upA), wrA, biasA, DvA, A_logs, kdA, hA, sdeA);
            yvB = s1_step<false>(&sR[1][tt][0], bf2f(*upB), wrB, biasB, DvB, A_logs, kdB, hB, sdeB);
        }
        upA += usA; upB += usB;
        yb[(size_t)tt * DI] = yvA;
        yb[(size_t)(CHUNK - 1 - tt) * DI] = yvB;
    }
    __syncthreads();   // drains vmcnt: all "=" stores committed before "+=" loads
    // second half: "+=" RMW
    #pragma unroll 2
    for (int tt = CHUNK / 2; tt < CHUNK; ++tt) {
        float yvA, yvB;
        if (ch) {
            yvA = s1_step<true>(&sR[0][tt][0], bf2f(*upA), wrA, biasA, DvA, A_logs, kdA, hA, sdeA);
            yvB = s1_step<true>(&sR[1][tt][0], bf2f(*upB), wrB, biasB, DvB, A_logs, kdB, hB, sdeB);
        } else {
            yvA = s1_step<false>(&sR[0][tt][0], bf2f(*upA), wrA, biasA, DvA, A_logs, kdA, hA, sdeA);
            yvB = s1_step<false>(&sR[1][tt][0], bf2f(*upB), wrB, biasB, DvB, A_logs, kdB, hB, sdeB);
        }
        upA += usA; upB += usB;
        yb[(size_t)tt * DI] += yvA;
        yb[(size_t)(CHUNK - 1 - tt) * DI] += yvB;
    }
    // carries
    carrG[((size_t)(g.b * Kn + g.kA) * NC + g.c) * DI + tid] = sdeA;
    carrG[((size_t)(g.b * Kn + g.kB) * NC + g.cB) * DI + tid] = sdeB;
    size_t hbA = ((size_t)(g.b * Kn + g.kA) * NC + g.c) * 16 * DI + tid;
    size_t hbB = ((size_t)(g.b * Kn + g.kB) * NC + g.cB) * 16 * DI + tid;
    #pragma unroll
    for (int n = 0; n < 16; ++n) {
        carrH[hbA + (size_t)n * DI] = f2bf(hA[n]);
        carrH[hbB + (size_t)n * DI] = f2bf(hB[n]);
    }
}

// ---------- kernel 5: scan phase 2 — combine carries across chunks ----------
__global__ __launch_bounds__(256) void k_scan2(const float* __restrict__ carrG,
                                               const float* __restrict__ A_logs,
                                               unsigned short* __restrict__ carrH) {
    int gid = blockIdx.x * 256 + threadIdx.x;
    int d = gid & 255;
    int n = (gid >> 8) & 15;
    int bk = gid >> 12;
    int k = bk & 3;
    float Ac = -__expf(A_logs[(size_t)(k * DI + d) * 16 + n]);
    size_t gbase = (size_t)bk * NC * DI + d;
    size_t hbase = ((size_t)bk * NC * 16 + n) * DI + d;
    const size_t hs = (size_t)16 * DI;
    float hr = 0.f;
    #pragma unroll
    for (int g = 0; g < NC / 32; ++g) {
        float sv[32];
        unsigned short hvv[32];
        #pragma unroll
        for (int j = 0; j < 32; ++j) sv[j] = carrG[gbase + (size_t)(g * 32 + j) * DI];
        #pragma unroll
        for (int j = 0; j < 32; ++j) hvv[j] = carrH[hbase + (size_t)(g * 32 + j) * hs];
        #pragma unroll
        for (int j = 0; j < 32; ++j) {
            float a = __expf(Ac * sv[j]);
            float he = bf2f(hvv[j]);
            carrH[hbase + (size_t)(g * 32 + j) * hs] = f2bf(hr);
            hr = a * hr + he;
        }
    }
}

// ---------- kernel 6: paired correction — LDS-staged records, interleaved dirs ----------
__global__ __launch_bounds__(256) void k_scan3p(const float* __restrict__ P,
                                                const float* __restrict__ dtw,
                                                const float* __restrict__ dtb,
                                                const float* __restrict__ A_logs,
                                                const unsigned short* __restrict__ carrH,
                                                float* __restrict__ y0,
                                                float* __restrict__ y1) {
    __shared__ float sR[2][CHUNK][44];
    int bid = blockIdx.x;
    int tid = threadIdx.x;
    WinGeom g = win_geom(bid);
    stage_recs(P, g, tid, sR);
    int kdA = g.kA * DI + tid, kdB = g.kB * DI + tid;
    float wrA[8], wrB[8];
    load_wr(dtw, kdA, wrA);
    load_wr(dtw, kdB, wrB);
    float biasA = dtb[kdA], biasB = dtb[kdB];
    bool ch = check_chain(A_logs, kdA) && check_chain(A_logs, kdB);
    float gA[16], h0A[16], gB[16], h0B[16];
    size_t hbA = ((size_t)(g.b * Kn + g.kA) * NC + g.c) * 16 * DI + tid;
    size_t hbB = ((size_t)(g.b * Kn + g.kB) * NC + g.cB) * 16 * DI + tid;
    #pragma unroll
    for (int n = 0; n < 16; ++n) {
        h0A[n] = bf2f(carrH[hbA + (size_t)n * DI]); gA[n] = h0A[n];
        h0B[n] = bf2f(carrH[hbB + (size_t)n * DI]); gB[n] = h0B[n];
    }
    float sdeA = 0.f, sdeB = 0.f;
    int p = g.kA;
    float* yb = (p == 0 ? y0 : y1) + ((size_t)g.b * LL + g.c * CHUNK) * DI + tid;
    // first half: A RMWs slots 0..15, B RMWs 16..31 (disjoint)
    #pragma unroll 2
    for (int tt = 0; tt < CHUNK / 2; ++tt) {
        float crA, crB;
        if (ch) {
            crA = s3_step<true>(&sR[0][tt][0], wrA, biasA, A_logs, kdA, gA, h0A, sdeA);
            crB = s3_step<true>(&sR[1][tt][0], wrB, biasB, A_logs, kdB, gB, h0B, sdeB);
        } else {
            crA = s3_step<false>(&sR[0][tt][0], wrA, biasA, A_logs, kdA, gA, h0A, sdeA);
            crB = s3_step<false>(&sR[1][tt][0], wrB, biasB, A_logs, kdB, gB, h0B, sdeB);
        }
        yb[(size_t)tt * DI] += crA;
        yb[(size_t)(CHUNK - 1 - tt) * DI] += crB;
    }
    __syncthreads();   // drain before the roles swap
    // second half: A RMWs 16..31, B RMWs 0..15 (disjoint again)
    #pragma unroll 2
    for (int tt = CHUNK / 2; tt < CHUNK; ++tt) {
        float crA, crB;
        if (ch) {
            crA = s3_step<true>(&sR[0][tt][0], wrA, biasA, A_logs, kdA, gA, h0A, sdeA);
            crB = s3_step<true>(&sR[1][tt][0], wrB, biasB, A_logs, kdB, gB, h0B, sdeB);
        } else {
            crA = s3_step<false>(&sR[0][tt][0], wrA, biasA, A_logs, kdA, gA, h0A, sdeA);
            crB = s3_step<false>(&sR[1][tt][0], wrB, biasB, A_logs, kdB, gB, h0B, sdeB);
        }
        yb[(size_t)tt * DI] += crA;
        yb[(size_t)(CHUNK - 1 - tt) * DI] += crB;
    }
}

// ---------- kernel 7: LayerNorm: y0 (in-place) + transposed y1 ----------
__global__ __launch_bounds__(256) void k_ln(float* __restrict__ y,
                                            const float* __restrict__ y1,
                                            const float* __restrict__ gamma,
                                            const float* __restrict__ beta) {
    __shared__ float s1[4], s2[4];
    int r = blockIdx.x;
    int tid = threadIdx.x;
    int b = r >> 12;
    int pos = r & 4095;
    int q = ((pos & 63) << 6) | (pos >> 6);   // y1 is stored in wh-scan order
    float v = y[(size_t)r * DI + tid] + y1[((size_t)b * LL + q) * DI + tid];
    float a = v, bsq = v * v;
    #pragma unroll
    for (int off = 32; off; off >>= 1) {
        a += __shfl_xor(a, off);
        bsq += __shfl_xor(bsq, off);
    }
    if ((tid & 63) == 0) { s1[tid >> 6] = a; s2[tid >> 6] = bsq; }
    __syncthreads();
    float S1 = s1[0] + s1[1] + s1[2] + s1[3];
    float S2 = s2[0] + s2[1] + s2[2] + s2[3];
    float mu = S1 * (1.f / 256.f);
    float var = S2 * (1.f / 256.f) - mu * mu;
    float rs = rsqrtf(var + 1e-5f);
    y[(size_t)r * DI + tid] = (v - mu) * rs * gamma[tid] + beta[tid];
}

// ---------- launch ----------
extern "C" void kernel_launch(void* const* d_in, const int* in_sizes, int n_in,
                              void* d_out, int out_size, void* d_ws, size_t ws_size,
                              hipStream_t stream) {
    const float* x    = (const float*)d_in[0];
    const float* ipw  = (const float*)d_in[1];
    const float* cw   = (const float*)d_in[2];
    const float* cb   = (const float*)d_in[3];
    const float* xpw  = (const float*)d_in[4];
    const float* dtw  = (const float*)d_in[5];
    const float* dtb  = (const float*)d_in[6];
    const float* alog = (const float*)d_in[7];
    const float* Ds   = (const float*)d_in[8];
    const float* gam  = (const float*)d_in[9];
    const float* bet  = (const float*)d_in[10];

    // ws layout (bytes):
    //   [0, 16777216)           carrH (bf16) -- aliases xls_pre (in_proj out, dead after conv)
    //   [16777216, 18874368)    carrG (fp32)
    //   [18874368, 27262976)    xcB   (bf16 B*L*DI)
    //   [27262976, 37748736)    P     (fp32 B*L*160, image order: [k*40: dts|B|C])
    //   [37748736, 54525952)    y1    (fp32 B*L*DI, pair{1,3} partial in wh-scan order)
    const size_t WS_NEED = 54525952;
    if (ws_size < WS_NEED) return;

    char* ws = (char*)d_ws;
    unsigned short* carrH = (unsigned short*)(ws + 0);
    float* carrG   = (float*)(ws + 16777216);
    float* xls_pre = (float*)(ws + 0);
    unsigned short* xcB = (unsigned short*)(ws + 18874368);
    float* P       = (float*)(ws + 27262976);
    float* y1      = (float*)(ws + 37748736);
    float* y       = (float*)d_out;

    k_inproj<<<256,   256, 0, stream>>>(x, ipw, xls_pre);
    k_conv  <<<512,   256, 0, stream>>>(xls_pre, cw, cb, xcB);
    k_proj  <<<256,   256, 0, stream>>>(xcB, xpw, P);
    k_scan1p<<<1024,  256, 0, stream>>>(xcB, P, dtw, dtb, alog, Ds, carrG, carrH, y, y1);
    k_scan2 <<<256,   256, 0, stream>>>(carrG, alog, carrH);
    k_scan3p<<<1024,  256, 0, stream>>>(P, dtw, dtb, alog, carrH, y, y1);
    k_ln    <<<16384, 256, 0, stream>>>(y, y1, gam, bet);
}

// Round 10
// 271.581 us; speedup vs baseline: 1.1051x; 1.1051x over previous
//
#include <hip/hip_runtime.h>

constexpr int Bn = 4;
constexpr int Hn = 64;
constexpr int Wn = 64;
constexpr int LL = Hn * Wn;     // 4096
constexpr int DM = 128;
constexpr int DI = 256;
constexpr int Nn = 16;
constexpr int Rn = 8;
constexpr int Kn = 4;
constexpr int NC = 128;         // chunks per (b,k) scan
constexpr int CHUNK = LL / NC;  // 32

using bf16x8 = __attribute__((ext_vector_type(8))) short;
using f32x4  = __attribute__((ext_vector_type(4))) float;

// ---------- helpers ----------
__device__ __forceinline__ float bf2f(unsigned short s) {
    return __uint_as_float(((unsigned int)s) << 16);
}
__device__ __forceinline__ unsigned short f2bf(float f) {
    unsigned int u = __float_as_uint(f);
    u += 0x7FFFu + ((u >> 16) & 1u);   // RNE
    return (unsigned short)(u >> 16);
}
__device__ __forceinline__ float softplus_f(float x) {
    if (x > 20.f) return x;
    return __logf(1.f + __expf(x));
}
// de = softplus(dtv), e1 = exp(-de) == 1/(1+exp(dtv))
__device__ __forceinline__ void softplus_e1(float dtv, float& de, float& e1) {
    float E = __expf(dtv);
    de = (dtv > 20.f) ? dtv : __logf(1.f + E);
    e1 = __builtin_amdgcn_rcpf(1.f + E);
}
// scan-order index t -> image position (row-major h*64+w)
__device__ __forceinline__ int posk(int k, int t) {
    int q = (k >= 2) ? (LL - 1 - t) : t;
    return (k & 1) ? (((q & 63) << 6) | (q >> 6)) : q;
}
__device__ __forceinline__ float dot8(const float wr[8], const float* __restrict__ rec) {
    float4 q0 = *(const float4*)rec;
    float4 q1 = *(const float4*)(rec + 4);
    return wr[0] * q0.x + wr[1] * q0.y + wr[2] * q0.z + wr[3] * q0.w
         + wr[4] * q1.x + wr[5] * q1.y + wr[6] * q1.z + wr[7] * q1.w;
}
__device__ __forceinline__ void load_wr(const float* __restrict__ dtw, int kd, float wr[8]) {
    float4 v0 = *(const float4*)(dtw + (size_t)kd * 8);
    float4 v1 = *(const float4*)(dtw + (size_t)kd * 8 + 4);
    wr[0] = v0.x; wr[1] = v0.y; wr[2] = v0.z; wr[3] = v0.w;
    wr[4] = v1.x; wr[5] = v1.y; wr[6] = v1.z; wr[7] = v1.w;
}
// e1^(n+1) for n=0..15, depth-4 tree (independent results)
__device__ __forceinline__ void pow16(float e1, float en[16]) {
    float e2 = e1 * e1, e4 = e2 * e2, e8 = e4 * e4;
    en[0] = e1;        en[1] = e2;        en[2] = e2 * e1;   en[3] = e4;
    en[4] = e4 * e1;   en[5] = e4 * e2;   en[6] = en[5] * e1; en[7] = e8;
    en[8] = e8 * e1;   en[9] = e8 * e2;   en[10] = en[9] * e1; en[11] = e8 * e4;
    en[12] = en[11] * e1; en[13] = en[11] * e2; en[14] = en[13] * e1; en[15] = e8 * e8;
}
// true iff -exp(A_logs[kd][n]) == -(n+1)  (A_logs = log(1..16) structure)
__device__ __forceinline__ bool check_chain(const float* __restrict__ A_logs, int kd) {
    float a0 = -__expf(A_logs[(size_t)kd * 16]);
    bool ok = fabsf(a0 + 1.f) < 1e-6f;
    #pragma unroll
    for (int n = 1; n < 16; ++n) {
        float an = -__expf(A_logs[(size_t)kd * 16 + n]);
        ok = ok && (fabsf(an - (float)(n + 1) * a0) <= 1e-4f * fabsf(an));
    }
    return ok;
}

// ---------- kernel 1: in_proj GEMM via MFMA bf16 ----------
__global__ __launch_bounds__(256) void k_inproj(const float* __restrict__ x,
                                                const float* __restrict__ wp,
                                                float* __restrict__ out) {
    __shared__ short sA[64][40];
    __shared__ short sW[256][40];
    int r0 = blockIdx.x * 64;
    int tid = threadIdx.x;
    int w = tid >> 6, lane = tid & 63;
    int ln15 = lane & 15, q8 = (lane >> 4) * 8;
    f32x4 acc[16];
    #pragma unroll
    for (int i = 0; i < 16; ++i) acc[i] = f32x4{0.f, 0.f, 0.f, 0.f};
    for (int kk = 0; kk < 4; ++kk) {
        {
            int r = tid >> 2, c0 = (tid & 3) * 8;
            const float* src = x + (size_t)(r0 + r) * DM + kk * 32 + c0;
            float4 v0 = *(const float4*)src;
            float4 v1 = *(const float4*)(src + 4);
            bf16x8 s;
            s[0] = (short)f2bf(v0.x); s[1] = (short)f2bf(v0.y);
            s[2] = (short)f2bf(v0.z); s[3] = (short)f2bf(v0.w);
            s[4] = (short)f2bf(v1.x); s[5] = (short)f2bf(v1.y);
            s[6] = (short)f2bf(v1.z); s[7] = (short)f2bf(v1.w);
            *(bf16x8*)&sA[r][c0] = s;
        }
        {
            const float* src = wp + (size_t)tid * DM + kk * 32;
            #pragma unroll
            for (int j = 0; j < 8; ++j) {
                float4 v = *(const float4*)(src + j * 4);
                sW[tid][j * 4 + 0] = (short)f2bf(v.x);
                sW[tid][j * 4 + 1] = (short)f2bf(v.y);
                sW[tid][j * 4 + 2] = (short)f2bf(v.z);
                sW[tid][j * 4 + 3] = (short)f2bf(v.w);
            }
        }
        __syncthreads();
        bf16x8 a = *(bf16x8*)&sA[w * 16 + ln15][q8];
        #pragma unroll
        for (int ni = 0; ni < 16; ++ni) {
            bf16x8 bfr = *(bf16x8*)&sW[ni * 16 + ln15][q8];
            acc[ni] = __builtin_amdgcn_mfma_f32_16x16x32_bf16(a, bfr, acc[ni], 0, 0, 0);
        }
        __syncthreads();
    }
    int rbase = r0 + w * 16 + (lane >> 4) * 4;
    #pragma unroll
    for (int ni = 0; ni < 16; ++ni)
        #pragma unroll
        for (int r = 0; r < 4; ++r)
            out[(size_t)(rbase + r) * DI + ni * 16 + ln15] = acc[ni][r];
}

// ---------- kernel 2: depthwise 3x3 conv + bias + SiLU, channel-last; emits bf16 ----------
__global__ __launch_bounds__(256) void k_conv(const float* __restrict__ xin,
                                              const float* __restrict__ cw,
                                              const float* __restrict__ cb,
                                              unsigned short* __restrict__ xoutB) {
    int bid = blockIdx.x;
    int hh   = bid & 1;
    int wblk = (bid >> 1) & 15;
    int dblk = (bid >> 5) & 3;
    int b    = bid >> 7;
    int tid = threadIdx.x;
    int d = dblk * 64 + (tid & 63);
    int w = wblk * 4 + (tid >> 6);
    const float* inb = xin + (size_t)b * LL * DI + d;
    unsigned short* outbB = xoutB + (size_t)b * LL * DI + d;
    float wg[9];
    #pragma unroll
    for (int i = 0; i < 9; ++i) wg[i] = cw[d * 9 + i];
    float bias = cb[d];
    #define LDV(hhh, www) ((((www) >= 0) && ((www) < Wn)) ? inb[(size_t)((hhh) * Wn + (www)) * DI] : 0.f)
    int hs = hh * 32;
    float r0[3], r1[3], r2[3];
    if (hs == 0) { r0[0] = r0[1] = r0[2] = 0.f; }
    else { r0[0] = LDV(hs - 1, w - 1); r0[1] = LDV(hs - 1, w); r0[2] = LDV(hs - 1, w + 1); }
    r1[0] = LDV(hs, w - 1); r1[1] = LDV(hs, w); r1[2] = LDV(hs, w + 1);
    r2[0] = LDV(hs + 1, w - 1); r2[1] = LDV(hs + 1, w); r2[2] = LDV(hs + 1, w + 1);
    for (int h = hs; h < hs + 32; ++h) {
        float acc = bias + wg[0] * r0[0] + wg[1] * r0[1] + wg[2] * r0[2]
                         + wg[3] * r1[0] + wg[4] * r1[1] + wg[5] * r1[2]
                         + wg[6] * r2[0] + wg[7] * r2[1] + wg[8] * r2[2];
        float sig = 1.f / (1.f + __expf(-acc));
        outbB[(size_t)(h * Wn + w) * DI] = f2bf(acc * sig);
        r0[0] = r1[0]; r0[1] = r1[1]; r0[2] = r1[2];
        r1[0] = r2[0]; r1[1] = r2[1]; r1[2] = r2[2];
        if (h + 2 < Hn) { r2[0] = LDV(h + 2, w - 1); r2[1] = LDV(h + 2, w); r2[2] = LDV(h + 2, w + 1); }
        else { r2[0] = r2[1] = r2[2] = 0.f; }
    }
    #undef LDV
}

// ---------- kernel 3: projection GEMM via MFMA bf16 ----------
__global__ __launch_bounds__(256) void k_proj(const unsigned short* __restrict__ xcB,
                                              const float* __restrict__ xpw,
                                              float* __restrict__ P) {
    __shared__ short sA[64][40];
    __shared__ short sW[160][40];
    int r0 = blockIdx.x * 64;
    int tid = threadIdx.x;
    int w = tid >> 6, lane = tid & 63;
    int ln15 = lane & 15, q8 = (lane >> 4) * 8;
    f32x4 acc[10];
    #pragma unroll
    for (int i = 0; i < 10; ++i) acc[i] = f32x4{0.f, 0.f, 0.f, 0.f};
    for (int kk = 0; kk < 8; ++kk) {
        {
            int r = tid >> 2, c0 = (tid & 3) * 8;
            *(bf16x8*)&sA[r][c0] =
                *(const bf16x8*)(xcB + (size_t)(r0 + r) * DI + kk * 32 + c0);
        }
        if (tid < 160) {
            const float* src = xpw + (size_t)tid * DI + kk * 32;
            #pragma unroll
            for (int j = 0; j < 8; ++j) {
                float4 v = *(const float4*)(src + j * 4);
                sW[tid][j * 4 + 0] = (short)f2bf(v.x);
                sW[tid][j * 4 + 1] = (short)f2bf(v.y);
                sW[tid][j * 4 + 2] = (short)f2bf(v.z);
                sW[tid][j * 4 + 3] = (short)f2bf(v.w);
            }
        }
        __syncthreads();
        bf16x8 a = *(bf16x8*)&sA[w * 16 + ln15][q8];
        #pragma unroll
        for (int ni = 0; ni < 10; ++ni) {
            bf16x8 bfr = *(bf16x8*)&sW[ni * 16 + ln15][q8];
            acc[ni] = __builtin_amdgcn_mfma_f32_16x16x32_bf16(a, bfr, acc[ni], 0, 0, 0);
        }
        __syncthreads();
    }
    int rbase = r0 + w * 16 + (lane >> 4) * 4;
    #pragma unroll
    for (int ni = 0; ni < 10; ++ni)
        #pragma unroll
        for (int r = 0; r < 4; ++r)
            P[(size_t)(rbase + r) * 160 + ni * 16 + ln15] = acc[ni][r];
}

// ---------- scan step cores ----------
template <bool CHAIN>
__device__ __forceinline__ float s1_step(const float* __restrict__ rec, float u,
                                         const float wr[8], float bias, float Dv,
                                         const float* __restrict__ A_logs, int kd,
                                         float h[16], float& sde) {
    float dtv = bias + dot8(wr, rec);
    float de, e1;
    softplus_e1(dtv, de, e1);
    float du = de * u;
    sde += de;
    float Ba[16], Ca[16];
    #pragma unroll
    for (int i = 0; i < 4; ++i) {
        float4 v = *(const float4*)(rec + 8 + i * 4);
        Ba[i * 4 + 0] = v.x; Ba[i * 4 + 1] = v.y; Ba[i * 4 + 2] = v.z; Ba[i * 4 + 3] = v.w;
        float4 w = *(const float4*)(rec + 24 + i * 4);
        Ca[i * 4 + 0] = w.x; Ca[i * 4 + 1] = w.y; Ca[i * 4 + 2] = w.z; Ca[i * 4 + 3] = w.w;
    }
    float yv[4];
    yv[0] = Dv * u; yv[1] = 0.f; yv[2] = 0.f; yv[3] = 0.f;
    if constexpr (CHAIN) {
        float en[16];
        pow16(e1, en);
        #pragma unroll
        for (int n = 0; n < 16; ++n) {
            h[n] = en[n] * h[n] + du * Ba[n];
            yv[n & 3] += h[n] * Ca[n];
        }
    } else {
        #pragma unroll
        for (int n = 0; n < 16; ++n) {
            float Ac = -__expf(A_logs[(size_t)kd * 16 + n]);
            h[n] = __expf(de * Ac) * h[n] + du * Ba[n];
            yv[n & 3] += h[n] * Ca[n];
        }
    }
    return (yv[0] + yv[1]) + (yv[2] + yv[3]);
}
// correction: g[n] = h0[n]*pe^(n+1) maintained incrementally; returns sum g*C
template <bool CHAIN>
__device__ __forceinline__ float s3_step(const float* __restrict__ rec,
                                         const float wr[8], float bias,
                                         const float* __restrict__ A_logs, int kd,
                                         float g[16], const float h0[16], float& sde) {
    float dtv = bias + dot8(wr, rec);
    float Ca[16];
    #pragma unroll
    for (int i = 0; i < 4; ++i) {
        float4 w = *(const float4*)(rec + 24 + i * 4);
        Ca[i * 4 + 0] = w.x; Ca[i * 4 + 1] = w.y; Ca[i * 4 + 2] = w.z; Ca[i * 4 + 3] = w.w;
    }
    float cv[4] = {0.f, 0.f, 0.f, 0.f};
    if constexpr (CHAIN) {
        float E = __expf(dtv);
        float e1 = __builtin_amdgcn_rcpf(1.f + E);
        float en[16];
        pow16(e1, en);
        #pragma unroll
        for (int n = 0; n < 16; ++n) {
            g[n] *= en[n];
            cv[n & 3] += g[n] * Ca[n];
        }
    } else {
        float de = softplus_f(dtv);
        sde += de;
        #pragma unroll
        for (int n = 0; n < 16; ++n) {
            float Ac = -__expf(A_logs[(size_t)kd * 16 + n]);
            cv[n & 3] += Ca[n] * __expf(Ac * sde) * h0[n];
        }
    }
    return (cv[0] + cv[1]) + (cv[2] + cv[3]);
}

// ---------- kernel 4: paired local scan — interleaved dirs, strided pointers, sY scratch ----------
// grid 1024 = 4b * 2pair * 128c ; pair0 = dirs {0,2} -> y0(=d_out), pair1 = {1,3} -> y1 (wh-scan)
__global__ __launch_bounds__(256, 4) void k_scan1p(const unsigned short* __restrict__ xcB,
                                                   const float* __restrict__ P,
                                                   const float* __restrict__ dtw,
                                                   const float* __restrict__ dtb,
                                                   const float* __restrict__ A_logs,
                                                   const float* __restrict__ Ds,
                                                   float* __restrict__ carrG,
                                                   unsigned short* __restrict__ carrH,
                                                   float* __restrict__ y0,
                                                   float* __restrict__ y1) {
    __shared__ float sY[CHUNK * 256];   // per-thread-private column scratch
    int bid = blockIdx.x;
    int c = bid & (NC - 1);
    int p = (bid >> 7) & 1;
    int b = bid >> 8;
    int tid = threadIdx.x;
    int kA = p, kB = p + 2, cB = NC - 1 - c;
    int kdA = kA * DI + tid, kdB = kB * DI + tid;
    float wrA[8], wrB[8];
    load_wr(dtw, kdA, wrA);
    load_wr(dtw, kdB, wrB);
    float biasA = dtb[kdA], biasB = dtb[kdB];
    float DvA = Ds[kdA], DvB = Ds[kdB];
    bool ch = check_chain(A_logs, kdA) && check_chain(A_logs, kdB);
    float hA[16], hB[16];
    #pragma unroll
    for (int n = 0; n < 16; ++n) { hA[n] = 0.f; hB[n] = 0.f; }
    float sdeA = 0.f, sdeB = 0.f;
    // affine geometry within chunk
    int t0A = c * CHUNK, t0B = cB * CHUNK;
    int pA0 = posk(kA, t0A), dpA = posk(kA, t0A + 1) - pA0;
    int pB0 = posk(kB, t0B), dpB = posk(kB, t0B + 1) - pB0;
    const float* recA = P + ((size_t)b * LL + pA0) * 160 + kA * 40;
    const float* recB = P + ((size_t)b * LL + pB0) * 160 + kB * 40;
    const unsigned short* upA = xcB + ((size_t)b * LL + pA0) * DI + tid;
    const unsigned short* upB = xcB + ((size_t)b * LL + pB0) * DI + tid;
    long rsA = (long)dpA * 160, rsB = (long)dpB * 160;
    long usA = (long)dpA * DI, usB = (long)dpB * DI;
    // tt in [0,16): first writer of both touched slots -> "="
    #define BODY(ASSIGN_OP)                                                                        \
        {                                                                                          \
            float yvA, yvB;                                                                        \
            if (ch) {                                                                              \
                yvA = s1_step<true>(recA, bf2f(*upA), wrA, biasA, DvA, A_logs, kdA, hA, sdeA);     \
                yvB = s1_step<true>(recB, bf2f(*upB), wrB, biasB, DvB, A_logs, kdB, hB, sdeB);     \
            } else {                                                                               \
                yvA = s1_step<false>(recA, bf2f(*upA), wrA, biasA, DvA, A_logs, kdA, hA, sdeA);    \
                yvB = s1_step<false>(recB, bf2f(*upB), wrB, biasB, DvB, A_logs, kdB, hB, sdeB);    \
            }                                                                                      \
            recA += rsA; recB += rsB; upA += usA; upB += usB;                                      \
            sY[tt * 256 + tid] ASSIGN_OP yvA;                                                      \
            sY[(CHUNK - 1 - tt) * 256 + tid] ASSIGN_OP yvB;                                        \
        }
    for (int tt = 0; tt < CHUNK / 2; ++tt) BODY(=)
    for (int tt = CHUNK / 2; tt < CHUNK; ++tt) BODY(+=)
    #undef BODY
    // carries
    carrG[((size_t)(b * Kn + kA) * NC + c) * DI + tid] = sdeA;
    carrG[((size_t)(b * Kn + kB) * NC + cB) * DI + tid] = sdeB;
    size_t hbA = ((size_t)(b * Kn + kA) * NC + c) * 16 * DI + tid;
    size_t hbB = ((size_t)(b * Kn + kB) * NC + cB) * 16 * DI + tid;
    #pragma unroll
    for (int n = 0; n < 16; ++n) {
        carrH[hbA + (size_t)n * DI] = f2bf(hA[n]);
        carrH[hbB + (size_t)n * DI] = f2bf(hB[n]);
    }
    // plain stores of the 32-position window (owner-exclusive)
    float* yb = (p == 0 ? y0 : y1) + ((size_t)b * LL + c * CHUNK) * DI + tid;
    for (int j = 0; j < CHUNK; ++j)
        yb[(size_t)j * DI] = sY[j * 256 + tid];
}

// ---------- kernel 5: scan phase 2 — combine carries across chunks ----------
__global__ __launch_bounds__(256) void k_scan2(const float* __restrict__ carrG,
                                               const float* __restrict__ A_logs,
                                               unsigned short* __restrict__ carrH) {
    int gid = blockIdx.x * 256 + threadIdx.x;
    int d = gid & 255;
    int n = (gid >> 8) & 15;
    int bk = gid >> 12;
    int k = bk & 3;
    float Ac = -__expf(A_logs[(size_t)(k * DI + d) * 16 + n]);
    size_t gbase = (size_t)bk * NC * DI + d;
    size_t hbase = ((size_t)bk * NC * 16 + n) * DI + d;
    const size_t hs = (size_t)16 * DI;
    float hr = 0.f;
    #pragma unroll
    for (int g = 0; g < NC / 32; ++g) {
        float sv[32];
        unsigned short hvv[32];
        #pragma unroll
        for (int j = 0; j < 32; ++j) sv[j] = carrG[gbase + (size_t)(g * 32 + j) * DI];
        #pragma unroll
        for (int j = 0; j < 32; ++j) hvv[j] = carrH[hbase + (size_t)(g * 32 + j) * hs];
        #pragma unroll
        for (int j = 0; j < 32; ++j) {
            float a = __expf(Ac * sv[j]);
            float he = bf2f(hvv[j]);
            carrH[hbase + (size_t)(g * 32 + j) * hs] = f2bf(hr);
            hr = a * hr + he;
        }
    }
}

// ---------- kernel 6: paired correction — interleaved dirs, strided pointers ----------
__global__ __launch_bounds__(256, 4) void k_scan3p(const float* __restrict__ P,
                                                   const float* __restrict__ dtw,
                                                   const float* __restrict__ dtb,
                                                   const float* __restrict__ A_logs,
                                                   const unsigned short* __restrict__ carrH,
                                                   float* __restrict__ y0,
                                                   float* __restrict__ y1) {
    __shared__ float sY[CHUNK * 256];
    int bid = blockIdx.x;
    int c = bid & (NC - 1);
    int p = (bid >> 7) & 1;
    int b = bid >> 8;
    int tid = threadIdx.x;
    int kA = p, kB = p + 2, cB = NC - 1 - c;
    int kdA = kA * DI + tid, kdB = kB * DI + tid;
    float wrA[8], wrB[8];
    load_wr(dtw, kdA, wrA);
    load_wr(dtw, kdB, wrB);
    float biasA = dtb[kdA], biasB = dtb[kdB];
    bool ch = check_chain(A_logs, kdA) && check_chain(A_logs, kdB);
    float gA[16], h0A[16], gB[16], h0B[16];
    size_t hbA = ((size_t)(b * Kn + kA) * NC + c) * 16 * DI + tid;
    size_t hbB = ((size_t)(b * Kn + kB) * NC + cB) * 16 * DI + tid;
    #pragma unroll
    for (int n = 0; n < 16; ++n) {
        h0A[n] = bf2f(carrH[hbA + (size_t)n * DI]); gA[n] = h0A[n];
        h0B[n] = bf2f(carrH[hbB + (size_t)n * DI]); gB[n] = h0B[n];
    }
    int t0A = c * CHUNK, t0B = cB * CHUNK;
    int pA0 = posk(kA, t0A), dpA = posk(kA, t0A + 1) - pA0;
    int pB0 = posk(kB, t0B), dpB = posk(kB, t0B + 1) - pB0;
    const float* recA = P + ((size_t)b * LL + pA0) * 160 + kA * 40;
    const float* recB = P + ((size_t)b * LL + pB0) * 160 + kB * 40;
    long rsA = (long)dpA * 160, rsB = (long)dpB * 160;
    float sdeA = 0.f, sdeB = 0.f;
    #define BODY3(ASSIGN_OP)                                                                       \
        {                                                                                          \
            float crA, crB;                                                                        \
            if (ch) {                                                                              \
                crA = s3_step<true>(recA, wrA, biasA, A_logs, kdA, gA, h0A, sdeA);                 \
                crB = s3_step<true>(recB, wrB, biasB, A_logs, kdB, gB, h0B, sdeB);                 \
            } else {                                                                               \
                crA = s3_step<false>(recA, wrA, biasA, A_logs, kdA, gA, h0A, sdeA);                \
                crB = s3_step<false>(recB, wrB, biasB, A_logs, kdB, gB, h0B, sdeB);                \
            }                                                                                      \
            recA += rsA; recB += rsB;                                                              \
            sY[tt * 256 + tid] ASSIGN_OP crA;                                                      \
            sY[(CHUNK - 1 - tt) * 256 + tid] ASSIGN_OP crB;                                        \
        }
    for (int tt = 0; tt < CHUNK / 2; ++tt) BODY3(=)
    for (int tt = CHUNK / 2; tt < CHUNK; ++tt) BODY3(+=)
    #undef BODY3
    float* yb = (p == 0 ? y0 : y1) + ((size_t)b * LL + c * CHUNK) * DI + tid;
    for (int j = 0; j < CHUNK; ++j)
        yb[(size_t)j * DI] += sY[j * 256 + tid];
}

// ---------- kernel 7: LayerNorm: y0 (in-place) + transposed y1 ----------
__global__ __launch_bounds__(256) void k_ln(float* __restrict__ y,
                                            const float* __restrict__ y1,
                                            const float* __restrict__ gamma,
                                            const float* __restrict__ beta) {
    __shared__ float s1[4], s2[4];
    int r = blockIdx.x;
    int tid = threadIdx.x;
    int b = r >> 12;
    int pos = r & 4095;
    int q = ((pos & 63) << 6) | (pos >> 6);   // y1 is stored in wh-scan order
    float v = y[(size_t)r * DI + tid] + y1[((size_t)b * LL + q) * DI + tid];
    float a = v, bsq = v * v;
    #pragma unroll
    for (int off = 32; off; off >>= 1) {
        a += __shfl_xor(a, off);
        bsq += __shfl_xor(bsq, off);
    }
    if ((tid & 63) == 0) { s1[tid >> 6] = a; s2[tid >> 6] = bsq; }
    __syncthreads();
    float S1 = s1[0] + s1[1] + s1[2] + s1[3];
    float S2 = s2[0] + s2[1] + s2[2] + s2[3];
    float mu = S1 * (1.f / 256.f);
    float var = S2 * (1.f / 256.f) - mu * mu;
    float rs = rsqrtf(var + 1e-5f);
    y[(size_t)r * DI + tid] = (v - mu) * rs * gamma[tid] + beta[tid];
}

// ---------- launch ----------
extern "C" void kernel_launch(void* const* d_in, const int* in_sizes, int n_in,
                              void* d_out, int out_size, void* d_ws, size_t ws_size,
                              hipStream_t stream) {
    const float* x    = (const float*)d_in[0];
    const float* ipw  = (const float*)d_in[1];
    const float* cw   = (const float*)d_in[2];
    const float* cb   = (const float*)d_in[3];
    const float* xpw  = (const float*)d_in[4];
    const float* dtw  = (const float*)d_in[5];
    const float* dtb  = (const float*)d_in[6];
    const float* alog = (const float*)d_in[7];
    const float* Ds   = (const float*)d_in[8];
    const float* gam  = (const float*)d_in[9];
    const float* bet  = (const float*)d_in[10];

    // ws layout (bytes):
    //   [0, 16777216)           carrH (bf16) -- aliases xls_pre (in_proj out, dead after conv)
    //   [16777216, 18874368)    carrG (fp32)
    //   [18874368, 27262976)    xcB   (bf16 B*L*DI)
    //   [27262976, 37748736)    P     (fp32 B*L*160, image order: [k*40: dts|B|C])
    //   [37748736, 54525952)    y1    (fp32 B*L*DI, pair{1,3} partial in wh-scan order)
    const size_t WS_NEED = 54525952;
    if (ws_size < WS_NEED) return;

    char* ws = (char*)d_ws;
    unsigned short* carrH = (unsigned short*)(ws + 0);
    float* carrG   = (float*)(ws + 16777216);
    float* xls_pre = (float*)(ws + 0);
    unsigned short* xcB = (unsigned short*)(ws + 18874368);
    float* P       = (float*)(ws + 27262976);
    float* y1      = (float*)(ws + 37748736);
    float* y       = (float*)d_out;

    k_inproj<<<256,   256, 0, stream>>>(x, ipw, xls_pre);
    k_conv  <<<512,   256, 0, stream>>>(xls_pre, cw, cb, xcB);
    k_proj  <<<256,   256, 0, stream>>>(xcB, xpw, P);
    k_scan1p<<<1024,  256, 0, stream>>>(xcB, P, dtw, dtb, alog, Ds, carrG, carrH, y, y1);
    k_scan2 <<<256,   256, 0, stream>>>(carrG, alog, carrH);
    k_scan3p<<<1024,  256, 0, stream>>>(P, dtw, dtb, alog, carrH, y, y1);
    k_ln    <<<16384, 256, 0, stream>>>(y, y1, gam, bet);
}

// Round 11
// 243.444 us; speedup vs baseline: 1.2328x; 1.1156x over previous
//
#include <hip/hip_runtime.h>

constexpr int Bn = 4;
constexpr int Hn = 64;
constexpr int Wn = 64;
constexpr int LL = Hn * Wn;     // 4096
constexpr int DM = 128;
constexpr int DI = 256;
constexpr int Nn = 16;
constexpr int Rn = 8;
constexpr int Kn = 4;
constexpr int NC = 128;         // chunks per (b,k) scan
constexpr int CHUNK = LL / NC;  // 32

using bf16x8 = __attribute__((ext_vector_type(8))) short;
using f32x4  = __attribute__((ext_vector_type(4))) float;

// ---------- helpers ----------
__device__ __forceinline__ float bf2f(unsigned short s) {
    return __uint_as_float(((unsigned int)s) << 16);
}
__device__ __forceinline__ unsigned short f2bf(float f) {
    unsigned int u = __float_as_uint(f);
    u += 0x7FFFu + ((u >> 16) & 1u);   // RNE
    return (unsigned short)(u >> 16);
}
__device__ __forceinline__ float softplus_f(float x) {
    if (x > 20.f) return x;
    return __logf(1.f + __expf(x));
}
// de = softplus(dtv), e1 = exp(-de) == 1/(1+exp(dtv))
__device__ __forceinline__ void softplus_e1(float dtv, float& de, float& e1) {
    float E = __expf(dtv);
    de = (dtv > 20.f) ? dtv : __logf(1.f + E);
    e1 = __builtin_amdgcn_rcpf(1.f + E);
}
// scan-order index t -> image position (row-major h*64+w)
__device__ __forceinline__ int posk(int k, int t) {
    int q = (k >= 2) ? (LL - 1 - t) : t;
    return (k & 1) ? (((q & 63) << 6) | (q >> 6)) : q;
}
__device__ __forceinline__ float dot8(const float wr[8], const float* __restrict__ rec) {
    float4 q0 = *(const float4*)rec;
    float4 q1 = *(const float4*)(rec + 4);
    return wr[0] * q0.x + wr[1] * q0.y + wr[2] * q0.z + wr[3] * q0.w
         + wr[4] * q1.x + wr[5] * q1.y + wr[6] * q1.z + wr[7] * q1.w;
}
__device__ __forceinline__ void load_wr(const float* __restrict__ dtw, int kd, float wr[8]) {
    float4 v0 = *(const float4*)(dtw + (size_t)kd * 8);
    float4 v1 = *(const float4*)(dtw + (size_t)kd * 8 + 4);
    wr[0] = v0.x; wr[1] = v0.y; wr[2] = v0.z; wr[3] = v0.w;
    wr[4] = v1.x; wr[5] = v1.y; wr[6] = v1.z; wr[7] = v1.w;
}
// e1^(n+1) for n=0..15, depth-4 tree (independent results)
__device__ __forceinline__ void pow16(float e1, float en[16]) {
    float e2 = e1 * e1, e4 = e2 * e2, e8 = e4 * e4;
    en[0] = e1;        en[1] = e2;        en[2] = e2 * e1;   en[3] = e4;
    en[4] = e4 * e1;   en[5] = e4 * e2;   en[6] = en[5] * e1; en[7] = e8;
    en[8] = e8 * e1;   en[9] = e8 * e2;   en[10] = en[9] * e1; en[11] = e8 * e4;
    en[12] = en[11] * e1; en[13] = en[11] * e2; en[14] = en[13] * e1; en[15] = e8 * e8;
}
// true iff -exp(A_logs[kd][n]) == -(n+1)  (A_logs = log(1..16) structure)
__device__ __forceinline__ bool check_chain(const float* __restrict__ A_logs, int kd) {
    float a0 = -__expf(A_logs[(size_t)kd * 16]);
    bool ok = fabsf(a0 + 1.f) < 1e-6f;
    #pragma unroll
    for (int n = 1; n < 16; ++n) {
        float an = -__expf(A_logs[(size_t)kd * 16 + n]);
        ok = ok && (fabsf(an - (float)(n + 1) * a0) <= 1e-4f * fabsf(an));
    }
    return ok;
}

// ---------- kernel 1: in_proj GEMM via MFMA bf16 ----------
__global__ __launch_bounds__(256) void k_inproj(const float* __restrict__ x,
                                                const float* __restrict__ wp,
                                                float* __restrict__ out) {
    __shared__ short sA[64][40];
    __shared__ short sW[256][40];
    int r0 = blockIdx.x * 64;
    int tid = threadIdx.x;
    int w = tid >> 6, lane = tid & 63;
    int ln15 = lane & 15, q8 = (lane >> 4) * 8;
    f32x4 acc[16];
    #pragma unroll
    for (int i = 0; i < 16; ++i) acc[i] = f32x4{0.f, 0.f, 0.f, 0.f};
    for (int kk = 0; kk < 4; ++kk) {
        {
            int r = tid >> 2, c0 = (tid & 3) * 8;
            const float* src = x + (size_t)(r0 + r) * DM + kk * 32 + c0;
            float4 v0 = *(const float4*)src;
            float4 v1 = *(const float4*)(src + 4);
            bf16x8 s;
            s[0] = (short)f2bf(v0.x); s[1] = (short)f2bf(v0.y);
            s[2] = (short)f2bf(v0.z); s[3] = (short)f2bf(v0.w);
            s[4] = (short)f2bf(v1.x); s[5] = (short)f2bf(v1.y);
            s[6] = (short)f2bf(v1.z); s[7] = (short)f2bf(v1.w);
            *(bf16x8*)&sA[r][c0] = s;
        }
        {
            const float* src = wp + (size_t)tid * DM + kk * 32;
            #pragma unroll
            for (int j = 0; j < 8; ++j) {
                float4 v = *(const float4*)(src + j * 4);
                sW[tid][j * 4 + 0] = (short)f2bf(v.x);
                sW[tid][j * 4 + 1] = (short)f2bf(v.y);
                sW[tid][j * 4 + 2] = (short)f2bf(v.z);
                sW[tid][j * 4 + 3] = (short)f2bf(v.w);
            }
        }
        __syncthreads();
        bf16x8 a = *(bf16x8*)&sA[w * 16 + ln15][q8];
        #pragma unroll
        for (int ni = 0; ni < 16; ++ni) {
            bf16x8 bfr = *(bf16x8*)&sW[ni * 16 + ln15][q8];
            acc[ni] = __builtin_amdgcn_mfma_f32_16x16x32_bf16(a, bfr, acc[ni], 0, 0, 0);
        }
        __syncthreads();
    }
    int rbase = r0 + w * 16 + (lane >> 4) * 4;
    #pragma unroll
    for (int ni = 0; ni < 16; ++ni)
        #pragma unroll
        for (int r = 0; r < 4; ++r)
            out[(size_t)(rbase + r) * DI + ni * 16 + ln15] = acc[ni][r];
}

// ---------- kernel 2: depthwise 3x3 conv + bias + SiLU, channel-last; emits bf16 ----------
__global__ __launch_bounds__(256) void k_conv(const float* __restrict__ xin,
                                              const float* __restrict__ cw,
                                              const float* __restrict__ cb,
                                              unsigned short* __restrict__ xoutB) {
    int bid = blockIdx.x;
    int hh   = bid & 1;
    int wblk = (bid >> 1) & 15;
    int dblk = (bid >> 5) & 3;
    int b    = bid >> 7;
    int tid = threadIdx.x;
    int d = dblk * 64 + (tid & 63);
    int w = wblk * 4 + (tid >> 6);
    const float* inb = xin + (size_t)b * LL * DI + d;
    unsigned short* outbB = xoutB + (size_t)b * LL * DI + d;
    float wg[9];
    #pragma unroll
    for (int i = 0; i < 9; ++i) wg[i] = cw[d * 9 + i];
    float bias = cb[d];
    #define LDV(hhh, www) ((((www) >= 0) && ((www) < Wn)) ? inb[(size_t)((hhh) * Wn + (www)) * DI] : 0.f)
    int hs = hh * 32;
    float r0[3], r1[3], r2[3];
    if (hs == 0) { r0[0] = r0[1] = r0[2] = 0.f; }
    else { r0[0] = LDV(hs - 1, w - 1); r0[1] = LDV(hs - 1, w); r0[2] = LDV(hs - 1, w + 1); }
    r1[0] = LDV(hs, w - 1); r1[1] = LDV(hs, w); r1[2] = LDV(hs, w + 1);
    r2[0] = LDV(hs + 1, w - 1); r2[1] = LDV(hs + 1, w); r2[2] = LDV(hs + 1, w + 1);
    for (int h = hs; h < hs + 32; ++h) {
        float acc = bias + wg[0] * r0[0] + wg[1] * r0[1] + wg[2] * r0[2]
                         + wg[3] * r1[0] + wg[4] * r1[1] + wg[5] * r1[2]
                         + wg[6] * r2[0] + wg[7] * r2[1] + wg[8] * r2[2];
        float sig = 1.f / (1.f + __expf(-acc));
        outbB[(size_t)(h * Wn + w) * DI] = f2bf(acc * sig);
        r0[0] = r1[0]; r0[1] = r1[1]; r0[2] = r1[2];
        r1[0] = r2[0]; r1[1] = r2[1]; r1[2] = r2[2];
        if (h + 2 < Hn) { r2[0] = LDV(h + 2, w - 1); r2[1] = LDV(h + 2, w); r2[2] = LDV(h + 2, w + 1); }
        else { r2[0] = r2[1] = r2[2] = 0.f; }
    }
    #undef LDV
}

// ---------- kernel 3: projection GEMM via MFMA bf16 ----------
__global__ __launch_bounds__(256) void k_proj(const unsigned short* __restrict__ xcB,
                                              const float* __restrict__ xpw,
                                              float* __restrict__ P) {
    __shared__ short sA[64][40];
    __shared__ short sW[160][40];
    int r0 = blockIdx.x * 64;
    int tid = threadIdx.x;
    int w = tid >> 6, lane = tid & 63;
    int ln15 = lane & 15, q8 = (lane >> 4) * 8;
    f32x4 acc[10];
    #pragma unroll
    for (int i = 0; i < 10; ++i) acc[i] = f32x4{0.f, 0.f, 0.f, 0.f};
    for (int kk = 0; kk < 8; ++kk) {
        {
            int r = tid >> 2, c0 = (tid & 3) * 8;
            *(bf16x8*)&sA[r][c0] =
                *(const bf16x8*)(xcB + (size_t)(r0 + r) * DI + kk * 32 + c0);
        }
        if (tid < 160) {
            const float* src = xpw + (size_t)tid * DI + kk * 32;
            #pragma unroll
            for (int j = 0; j < 8; ++j) {
                float4 v = *(const float4*)(src + j * 4);
                sW[tid][j * 4 + 0] = (short)f2bf(v.x);
                sW[tid][j * 4 + 1] = (short)f2bf(v.y);
                sW[tid][j * 4 + 2] = (short)f2bf(v.z);
                sW[tid][j * 4 + 3] = (short)f2bf(v.w);
            }
        }
        __syncthreads();
        bf16x8 a = *(bf16x8*)&sA[w * 16 + ln15][q8];
        #pragma unroll
        for (int ni = 0; ni < 10; ++ni) {
            bf16x8 bfr = *(bf16x8*)&sW[ni * 16 + ln15][q8];
            acc[ni] = __builtin_amdgcn_mfma_f32_16x16x32_bf16(a, bfr, acc[ni], 0, 0, 0);
        }
        __syncthreads();
    }
    int rbase = r0 + w * 16 + (lane >> 4) * 4;
    #pragma unroll
    for (int ni = 0; ni < 10; ++ni)
        #pragma unroll
        for (int r = 0; r < 4; ++r)
            P[(size_t)(rbase + r) * 160 + ni * 16 + ln15] = acc[ni][r];
}

// ---------- scan step cores ----------
template <bool CHAIN>
__device__ __forceinline__ float s1_step(const float* __restrict__ rec, float u,
                                         const float wr[8], float bias, float Dv,
                                         const float* __restrict__ A_logs, int kd,
                                         float h[16], float& sde) {
    float dtv = bias + dot8(wr, rec);
    float de, e1;
    softplus_e1(dtv, de, e1);
    float du = de * u;
    sde += de;
    float Ba[16], Ca[16];
    #pragma unroll
    for (int i = 0; i < 4; ++i) {
        float4 v = *(const float4*)(rec + 8 + i * 4);
        Ba[i * 4 + 0] = v.x; Ba[i * 4 + 1] = v.y; Ba[i * 4 + 2] = v.z; Ba[i * 4 + 3] = v.w;
        float4 w = *(const float4*)(rec + 24 + i * 4);
        Ca[i * 4 + 0] = w.x; Ca[i * 4 + 1] = w.y; Ca[i * 4 + 2] = w.z; Ca[i * 4 + 3] = w.w;
    }
    float yv[4];
    yv[0] = Dv * u; yv[1] = 0.f; yv[2] = 0.f; yv[3] = 0.f;
    if constexpr (CHAIN) {
        float en[16];
        pow16(e1, en);
        #pragma unroll
        for (int n = 0; n < 16; ++n) {
            h[n] = en[n] * h[n] + du * Ba[n];
            yv[n & 3] += h[n] * Ca[n];
        }
    } else {
        #pragma unroll
        for (int n = 0; n < 16; ++n) {
            float Ac = -__expf(A_logs[(size_t)kd * 16 + n]);
            h[n] = __expf(de * Ac) * h[n] + du * Ba[n];
            yv[n & 3] += h[n] * Ca[n];
        }
    }
    return (yv[0] + yv[1]) + (yv[2] + yv[3]);
}
// correction: g[n] = h0[n]*pe^(n+1) maintained incrementally; returns sum g*C
template <bool CHAIN>
__device__ __forceinline__ float s3_step(const float* __restrict__ rec,
                                         const float wr[8], float bias,
                                         const float* __restrict__ A_logs, int kd,
                                         float g[16], const float h0[16], float& sde) {
    float dtv = bias + dot8(wr, rec);
    float Ca[16];
    #pragma unroll
    for (int i = 0; i < 4; ++i) {
        float4 w = *(const float4*)(rec + 24 + i * 4);
        Ca[i * 4 + 0] = w.x; Ca[i * 4 + 1] = w.y; Ca[i * 4 + 2] = w.z; Ca[i * 4 + 3] = w.w;
    }
    float cv[4] = {0.f, 0.f, 0.f, 0.f};
    if constexpr (CHAIN) {
        float E = __expf(dtv);
        float e1 = __builtin_amdgcn_rcpf(1.f + E);
        float en[16];
        pow16(e1, en);
        #pragma unroll
        for (int n = 0; n < 16; ++n) {
            g[n] *= en[n];
            cv[n & 3] += g[n] * Ca[n];
        }
    } else {
        float de = softplus_f(dtv);
        sde += de;
        #pragma unroll
        for (int n = 0; n < 16; ++n) {
            float Ac = -__expf(A_logs[(size_t)kd * 16 + n]);
            cv[n & 3] += Ca[n] * __expf(Ac * sde) * h0[n];
        }
    }
    return (cv[0] + cv[1]) + (cv[2] + cv[3]);
}

// ---------- kernel 4: paired local scan — R7 skeleton (outer ch branch, single
// interleaved loop, sY zero-init + "+=") with strided pointers + pow16 ----------
// grid 1024 = 4b * 2pair * 128c ; pair0 = dirs {0,2} -> y0(=d_out), pair1 = {1,3} -> y1 (wh-scan)
__global__ __launch_bounds__(256, 4) void k_scan1p(const unsigned short* __restrict__ xcB,
                                                   const float* __restrict__ P,
                                                   const float* __restrict__ dtw,
                                                   const float* __restrict__ dtb,
                                                   const float* __restrict__ A_logs,
                                                   const float* __restrict__ Ds,
                                                   float* __restrict__ carrG,
                                                   unsigned short* __restrict__ carrH,
                                                   float* __restrict__ y0,
                                                   float* __restrict__ y1) {
    __shared__ float sY[CHUNK * 256];   // per-thread-private column scratch
    int bid = blockIdx.x;
    int c = bid & (NC - 1);
    int p = (bid >> 7) & 1;
    int b = bid >> 8;
    int tid = threadIdx.x;
    int kA = p, kB = p + 2, cB = NC - 1 - c;
    int kdA = kA * DI + tid, kdB = kB * DI + tid;
    float wrA[8], wrB[8];
    load_wr(dtw, kdA, wrA);
    load_wr(dtw, kdB, wrB);
    float biasA = dtb[kdA], biasB = dtb[kdB];
    float DvA = Ds[kdA], DvB = Ds[kdB];
    bool ch = check_chain(A_logs, kdA) && check_chain(A_logs, kdB);
    float hA[16], hB[16];
    #pragma unroll
    for (int n = 0; n < 16; ++n) { hA[n] = 0.f; hB[n] = 0.f; }
    float sdeA = 0.f, sdeB = 0.f;
    for (int j = 0; j < CHUNK; ++j) sY[j * 256 + tid] = 0.f;
    // affine geometry within chunk
    int t0A = c * CHUNK, t0B = cB * CHUNK;
    int pA0 = posk(kA, t0A), dpA = posk(kA, t0A + 1) - pA0;
    int pB0 = posk(kB, t0B), dpB = posk(kB, t0B + 1) - pB0;
    const float* recA = P + ((size_t)b * LL + pA0) * 160 + kA * 40;
    const float* recB = P + ((size_t)b * LL + pB0) * 160 + kB * 40;
    const unsigned short* upA = xcB + ((size_t)b * LL + pA0) * DI + tid;
    const unsigned short* upB = xcB + ((size_t)b * LL + pB0) * DI + tid;
    long rsA = (long)dpA * 160, rsB = (long)dpB * 160;
    long usA = (long)dpA * DI, usB = (long)dpB * DI;
    if (ch) {
        for (int tt = 0; tt < CHUNK; ++tt) {
            float yvA = s1_step<true>(recA, bf2f(*upA), wrA, biasA, DvA, A_logs, kdA, hA, sdeA);
            float yvB = s1_step<true>(recB, bf2f(*upB), wrB, biasB, DvB, A_logs, kdB, hB, sdeB);
            recA += rsA; recB += rsB; upA += usA; upB += usB;
            sY[tt * 256 + tid] += yvA;
            sY[(CHUNK - 1 - tt) * 256 + tid] += yvB;
        }
    } else {
        for (int tt = 0; tt < CHUNK; ++tt) {
            float yvA = s1_step<false>(recA, bf2f(*upA), wrA, biasA, DvA, A_logs, kdA, hA, sdeA);
            float yvB = s1_step<false>(recB, bf2f(*upB), wrB, biasB, DvB, A_logs, kdB, hB, sdeB);
            recA += rsA; recB += rsB; upA += usA; upB += usB;
            sY[tt * 256 + tid] += yvA;
            sY[(CHUNK - 1 - tt) * 256 + tid] += yvB;
        }
    }
    // carries
    carrG[((size_t)(b * Kn + kA) * NC + c) * DI + tid] = sdeA;
    carrG[((size_t)(b * Kn + kB) * NC + cB) * DI + tid] = sdeB;
    size_t hbA = ((size_t)(b * Kn + kA) * NC + c) * 16 * DI + tid;
    size_t hbB = ((size_t)(b * Kn + kB) * NC + cB) * 16 * DI + tid;
    #pragma unroll
    for (int n = 0; n < 16; ++n) {
        carrH[hbA + (size_t)n * DI] = f2bf(hA[n]);
        carrH[hbB + (size_t)n * DI] = f2bf(hB[n]);
    }
    // plain stores of the 32-position window (owner-exclusive)
    float* yb = (p == 0 ? y0 : y1) + ((size_t)b * LL + c * CHUNK) * DI + tid;
    for (int j = 0; j < CHUNK; ++j)
        yb[(size_t)j * DI] = sY[j * 256 + tid];
}

// ---------- kernel 5: scan phase 2 — combine carries across chunks ----------
__global__ __launch_bounds__(256) void k_scan2(const float* __restrict__ carrG,
                                               const float* __restrict__ A_logs,
                                               unsigned short* __restrict__ carrH) {
    int gid = blockIdx.x * 256 + threadIdx.x;
    int d = gid & 255;
    int n = (gid >> 8) & 15;
    int bk = gid >> 12;
    int k = bk & 3;
    float Ac = -__expf(A_logs[(size_t)(k * DI + d) * 16 + n]);
    size_t gbase = (size_t)bk * NC * DI + d;
    size_t hbase = ((size_t)bk * NC * 16 + n) * DI + d;
    const size_t hs = (size_t)16 * DI;
    float hr = 0.f;
    #pragma unroll
    for (int g = 0; g < NC / 32; ++g) {
        float sv[32];
        unsigned short hvv[32];
        #pragma unroll
        for (int j = 0; j < 32; ++j) sv[j] = carrG[gbase + (size_t)(g * 32 + j) * DI];
        #pragma unroll
        for (int j = 0; j < 32; ++j) hvv[j] = carrH[hbase + (size_t)(g * 32 + j) * hs];
        #pragma unroll
        for (int j = 0; j < 32; ++j) {
            float a = __expf(Ac * sv[j]);
            float he = bf2f(hvv[j]);
            carrH[hbase + (size_t)(g * 32 + j) * hs] = f2bf(hr);
            hr = a * hr + he;
        }
    }
}

// ---------- kernel 6: paired correction — R7 skeleton + strided pointers + g-update ----------
__global__ __launch_bounds__(256, 4) void k_scan3p(const float* __restrict__ P,
                                                   const float* __restrict__ dtw,
                                                   const float* __restrict__ dtb,
                                                   const float* __restrict__ A_logs,
                                                   const unsigned short* __restrict__ carrH,
                                                   float* __restrict__ y0,
                                                   float* __restrict__ y1) {
    __shared__ float sY[CHUNK * 256];
    int bid = blockIdx.x;
    int c = bid & (NC - 1);
    int p = (bid >> 7) & 1;
    int b = bid >> 8;
    int tid = threadIdx.x;
    int kA = p, kB = p + 2, cB = NC - 1 - c;
    int kdA = kA * DI + tid, kdB = kB * DI + tid;
    float wrA[8], wrB[8];
    load_wr(dtw, kdA, wrA);
    load_wr(dtw, kdB, wrB);
    float biasA = dtb[kdA], biasB = dtb[kdB];
    bool ch = check_chain(A_logs, kdA) && check_chain(A_logs, kdB);
    float gA[16], h0A[16], gB[16], h0B[16];
    size_t hbA = ((size_t)(b * Kn + kA) * NC + c) * 16 * DI + tid;
    size_t hbB = ((size_t)(b * Kn + kB) * NC + cB) * 16 * DI + tid;
    #pragma unroll
    for (int n = 0; n < 16; ++n) {
        h0A[n] = bf2f(carrH[hbA + (size_t)n * DI]); gA[n] = h0A[n];
        h0B[n] = bf2f(carrH[hbB + (size_t)n * DI]); gB[n] = h0B[n];
    }
    for (int j = 0; j < CHUNK; ++j) sY[j * 256 + tid] = 0.f;
    int t0A = c * CHUNK, t0B = cB * CHUNK;
    int pA0 = posk(kA, t0A), dpA = posk(kA, t0A + 1) - pA0;
    int pB0 = posk(kB, t0B), dpB = posk(kB, t0B + 1) - pB0;
    const float* recA = P + ((size_t)b * LL + pA0) * 160 + kA * 40;
    const float* recB = P + ((size_t)b * LL + pB0) * 160 + kB * 40;
    long rsA = (long)dpA * 160, rsB = (long)dpB * 160;
    float sdeA = 0.f, sdeB = 0.f;
    if (ch) {
        for (int tt = 0; tt < CHUNK; ++tt) {
            float crA = s3_step<true>(recA, wrA, biasA, A_logs, kdA, gA, h0A, sdeA);
            float crB = s3_step<true>(recB, wrB, biasB, A_logs, kdB, gB, h0B, sdeB);
            recA += rsA; recB += rsB;
            sY[tt * 256 + tid] += crA;
            sY[(CHUNK - 1 - tt) * 256 + tid] += crB;
        }
    } else {
        for (int tt = 0; tt < CHUNK; ++tt) {
            float crA = s3_step<false>(recA, wrA, biasA, A_logs, kdA, gA, h0A, sdeA);
            float crB = s3_step<false>(recB, wrB, biasB, A_logs, kdB, gB, h0B, sdeB);
            recA += rsA; recB += rsB;
            sY[tt * 256 + tid] += crA;
            sY[(CHUNK - 1 - tt) * 256 + tid] += crB;
        }
    }
    float* yb = (p == 0 ? y0 : y1) + ((size_t)b * LL + c * CHUNK) * DI + tid;
    for (int j = 0; j < CHUNK; ++j)
        yb[(size_t)j * DI] += sY[j * 256 + tid];
}

// ---------- kernel 7: LayerNorm: y0 (in-place) + transposed y1 ----------
__global__ __launch_bounds__(256) void k_ln(float* __restrict__ y,
                                            const float* __restrict__ y1,
                                            const float* __restrict__ gamma,
                                            const float* __restrict__ beta) {
    __shared__ float s1[4], s2[4];
    int r = blockIdx.x;
    int tid = threadIdx.x;
    int b = r >> 12;
    int pos = r & 4095;
    int q = ((pos & 63) << 6) | (pos >> 6);   // y1 is stored in wh-scan order
    float v = y[(size_t)r * DI + tid] + y1[((size_t)b * LL + q) * DI + tid];
    float a = v, bsq = v * v;
    #pragma unroll
    for (int off = 32; off; off >>= 1) {
        a += __shfl_xor(a, off);
        bsq += __shfl_xor(bsq, off);
    }
    if ((tid & 63) == 0) { s1[tid >> 6] = a; s2[tid >> 6] = bsq; }
    __syncthreads();
    float S1 = s1[0] + s1[1] + s1[2] + s1[3];
    float S2 = s2[0] + s2[1] + s2[2] + s2[3];
    float mu = S1 * (1.f / 256.f);
    float var = S2 * (1.f / 256.f) - mu * mu;
    float rs = rsqrtf(var + 1e-5f);
    y[(size_t)r * DI + tid] = (v - mu) * rs * gamma[tid] + beta[tid];
}

// ---------- launch ----------
extern "C" void kernel_launch(void* const* d_in, const int* in_sizes, int n_in,
                              void* d_out, int out_size, void* d_ws, size_t ws_size,
                              hipStream_t stream) {
    const float* x    = (const float*)d_in[0];
    const float* ipw  = (const float*)d_in[1];
    const float* cw   = (const float*)d_in[2];
    const float* cb   = (const float*)d_in[3];
    const float* xpw  = (const float*)d_in[4];
    const float* dtw  = (const float*)d_in[5];
    const float* dtb  = (const float*)d_in[6];
    const float* alog = (const float*)d_in[7];
    const float* Ds   = (const float*)d_in[8];
    const float* gam  = (const float*)d_in[9];
    const float* bet  = (const float*)d_in[10];

    // ws layout (bytes):
    //   [0, 16777216)           carrH (bf16) -- aliases xls_pre (in_proj out, dead after conv)
    //   [16777216, 18874368)    carrG (fp32)
    //   [18874368, 27262976)    xcB   (bf16 B*L*DI)
    //   [27262976, 37748736)    P     (fp32 B*L*160, image order: [k*40: dts|B|C])
    //   [37748736, 54525952)    y1    (fp32 B*L*DI, pair{1,3} partial in wh-scan order)
    const size_t WS_NEED = 54525952;
    if (ws_size < WS_NEED) return;

    char* ws = (char*)d_ws;
    unsigned short* carrH = (unsigned short*)(ws + 0);
    float* carrG   = (float*)(ws + 16777216);
    float* xls_pre = (float*)(ws + 0);
    unsigned short* xcB = (unsigned short*)(ws + 18874368);
    float* P       = (float*)(ws + 27262976);
    float* y1      = (float*)(ws + 37748736);
    float* y       = (float*)d_out;

    k_inproj<<<256,   256, 0, stream>>>(x, ipw, xls_pre);
    k_conv  <<<512,   256, 0, stream>>>(xls_pre, cw, cb, xcB);
    k_proj  <<<256,   256, 0, stream>>>(xcB, xpw, P);
    k_scan1p<<<1024,  256, 0, stream>>>(xcB, P, dtw, dtb, alog, Ds, carrG, carrH, y, y1);
    k_scan2 <<<256,   256, 0, stream>>>(carrG, alog, carrH);
    k_scan3p<<<1024,  256, 0, stream>>>(P, dtw, dtb, alog, carrH, y, y1);
    k_ln    <<<16384, 256, 0, stream>>>(y, y1, gam, bet);
}

// Round 12
// 234.495 us; speedup vs baseline: 1.2798x; 1.0382x over previous
//
#include <hip/hip_runtime.h>

constexpr int Bn = 4;
constexpr int Hn = 64;
constexpr int Wn = 64;
constexpr int LL = Hn * Wn;     // 4096
constexpr int DM = 128;
constexpr int DI = 256;
constexpr int Nn = 16;
constexpr int Rn = 8;
constexpr int Kn = 4;
constexpr int NC = 128;         // chunks per (b,k) scan
constexpr int CHUNK = LL / NC;  // 32

using bf16x8 = __attribute__((ext_vector_type(8))) short;
using f32x4  = __attribute__((ext_vector_type(4))) float;

// ---------- helpers ----------
__device__ __forceinline__ float bf2f(unsigned short s) {
    return __uint_as_float(((unsigned int)s) << 16);
}
__device__ __forceinline__ unsigned short f2bf(float f) {
    unsigned int u = __float_as_uint(f);
    u += 0x7FFFu + ((u >> 16) & 1u);   // RNE
    return (unsigned short)(u >> 16);
}
__device__ __forceinline__ float softplus_f(float x) {
    if (x > 20.f) return x;
    return __logf(1.f + __expf(x));
}
// de = softplus(dtv), e1 = exp(-de) == 1/(1+exp(dtv))
__device__ __forceinline__ void softplus_e1(float dtv, float& de, float& e1) {
    float E = __expf(dtv);
    de = (dtv > 20.f) ? dtv : __logf(1.f + E);
    e1 = __builtin_amdgcn_rcpf(1.f + E);
}
// scan-order index t -> image position (row-major h*64+w)
__device__ __forceinline__ int posk(int k, int t) {
    int q = (k >= 2) ? (LL - 1 - t) : t;
    return (k & 1) ? (((q & 63) << 6) | (q >> 6)) : q;
}
__device__ __forceinline__ float dot8(const float wr[8], const float* __restrict__ rec) {
    float4 q0 = *(const float4*)rec;
    float4 q1 = *(const float4*)(rec + 4);
    return wr[0] * q0.x + wr[1] * q0.y + wr[2] * q0.z + wr[3] * q0.w
         + wr[4] * q1.x + wr[5] * q1.y + wr[6] * q1.z + wr[7] * q1.w;
}
__device__ __forceinline__ void load_wr(const float* __restrict__ dtw, int kd, float wr[8]) {
    float4 v0 = *(const float4*)(dtw + (size_t)kd * 8);
    float4 v1 = *(const float4*)(dtw + (size_t)kd * 8 + 4);
    wr[0] = v0.x; wr[1] = v0.y; wr[2] = v0.z; wr[3] = v0.w;
    wr[4] = v1.x; wr[5] = v1.y; wr[6] = v1.z; wr[7] = v1.w;
}
// e1^(n+1) for n=0..15, depth-4 tree (independent results)
__device__ __forceinline__ void pow16(float e1, float en[16]) {
    float e2 = e1 * e1, e4 = e2 * e2, e8 = e4 * e4;
    en[0] = e1;        en[1] = e2;        en[2] = e2 * e1;   en[3] = e4;
    en[4] = e4 * e1;   en[5] = e4 * e2;   en[6] = en[5] * e1; en[7] = e8;
    en[8] = e8 * e1;   en[9] = e8 * e2;   en[10] = en[9] * e1; en[11] = e8 * e4;
    en[12] = en[11] * e1; en[13] = en[11] * e2; en[14] = en[13] * e1; en[15] = e8 * e8;
}
// true iff -exp(A_logs[kd][n]) == -(n+1)  (A_logs = log(1..16) structure)
__device__ __forceinline__ bool check_chain(const float* __restrict__ A_logs, int kd) {
    float a0 = -__expf(A_logs[(size_t)kd * 16]);
    bool ok = fabsf(a0 + 1.f) < 1e-6f;
    #pragma unroll
    for (int n = 1; n < 16; ++n) {
        float an = -__expf(A_logs[(size_t)kd * 16 + n]);
        ok = ok && (fabsf(an - (float)(n + 1) * a0) <= 1e-4f * fabsf(an));
    }
    return ok;
}

// ---------- kernel 1: in_proj GEMM via MFMA bf16 ----------
__global__ __launch_bounds__(256) void k_inproj(const float* __restrict__ x,
                                                const float* __restrict__ wp,
                                                float* __restrict__ out) {
    __shared__ short sA[64][40];
    __shared__ short sW[256][40];
    int r0 = blockIdx.x * 64;
    int tid = threadIdx.x;
    int w = tid >> 6, lane = tid & 63;
    int ln15 = lane & 15, q8 = (lane >> 4) * 8;
    f32x4 acc[16];
    #pragma unroll
    for (int i = 0; i < 16; ++i) acc[i] = f32x4{0.f, 0.f, 0.f, 0.f};
    for (int kk = 0; kk < 4; ++kk) {
        {
            int r = tid >> 2, c0 = (tid & 3) * 8;
            const float* src = x + (size_t)(r0 + r) * DM + kk * 32 + c0;
            float4 v0 = *(const float4*)src;
            float4 v1 = *(const float4*)(src + 4);
            bf16x8 s;
            s[0] = (short)f2bf(v0.x); s[1] = (short)f2bf(v0.y);
            s[2] = (short)f2bf(v0.z); s[3] = (short)f2bf(v0.w);
            s[4] = (short)f2bf(v1.x); s[5] = (short)f2bf(v1.y);
            s[6] = (short)f2bf(v1.z); s[7] = (short)f2bf(v1.w);
            *(bf16x8*)&sA[r][c0] = s;
        }
        {
            const float* src = wp + (size_t)tid * DM + kk * 32;
            #pragma unroll
            for (int j = 0; j < 8; ++j) {
                float4 v = *(const float4*)(src + j * 4);
                sW[tid][j * 4 + 0] = (short)f2bf(v.x);
                sW[tid][j * 4 + 1] = (short)f2bf(v.y);
                sW[tid][j * 4 + 2] = (short)f2bf(v.z);
                sW[tid][j * 4 + 3] = (short)f2bf(v.w);
            }
        }
        __syncthreads();
        bf16x8 a = *(bf16x8*)&sA[w * 16 + ln15][q8];
        #pragma unroll
        for (int ni = 0; ni < 16; ++ni) {
            bf16x8 bfr = *(bf16x8*)&sW[ni * 16 + ln15][q8];
            acc[ni] = __builtin_amdgcn_mfma_f32_16x16x32_bf16(a, bfr, acc[ni], 0, 0, 0);
        }
        __syncthreads();
    }
    int rbase = r0 + w * 16 + (lane >> 4) * 4;
    #pragma unroll
    for (int ni = 0; ni < 16; ++ni)
        #pragma unroll
        for (int r = 0; r < 4; ++r)
            out[(size_t)(rbase + r) * DI + ni * 16 + ln15] = acc[ni][r];
}

// ---------- kernel 2: depthwise 3x3 conv + bias + SiLU, channel-last; emits bf16 ----------
__global__ __launch_bounds__(256) void k_conv(const float* __restrict__ xin,
                                              const float* __restrict__ cw,
                                              const float* __restrict__ cb,
                                              unsigned short* __restrict__ xoutB) {
    int bid = blockIdx.x;
    int hh   = bid & 1;
    int wblk = (bid >> 1) & 15;
    int dblk = (bid >> 5) & 3;
    int b    = bid >> 7;
    int tid = threadIdx.x;
    int d = dblk * 64 + (tid & 63);
    int w = wblk * 4 + (tid >> 6);
    const float* inb = xin + (size_t)b * LL * DI + d;
    unsigned short* outbB = xoutB + (size_t)b * LL * DI + d;
    float wg[9];
    #pragma unroll
    for (int i = 0; i < 9; ++i) wg[i] = cw[d * 9 + i];
    float bias = cb[d];
    #define LDV(hhh, www) ((((www) >= 0) && ((www) < Wn)) ? inb[(size_t)((hhh) * Wn + (www)) * DI] : 0.f)
    int hs = hh * 32;
    float r0[3], r1[3], r2[3];
    if (hs == 0) { r0[0] = r0[1] = r0[2] = 0.f; }
    else { r0[0] = LDV(hs - 1, w - 1); r0[1] = LDV(hs - 1, w); r0[2] = LDV(hs - 1, w + 1); }
    r1[0] = LDV(hs, w - 1); r1[1] = LDV(hs, w); r1[2] = LDV(hs, w + 1);
    r2[0] = LDV(hs + 1, w - 1); r2[1] = LDV(hs + 1, w); r2[2] = LDV(hs + 1, w + 1);
    for (int h = hs; h < hs + 32; ++h) {
        float acc = bias + wg[0] * r0[0] + wg[1] * r0[1] + wg[2] * r0[2]
                         + wg[3] * r1[0] + wg[4] * r1[1] + wg[5] * r1[2]
                         + wg[6] * r2[0] + wg[7] * r2[1] + wg[8] * r2[2];
        float sig = 1.f / (1.f + __expf(-acc));
        outbB[(size_t)(h * Wn + w) * DI] = f2bf(acc * sig);
        r0[0] = r1[0]; r0[1] = r1[1]; r0[2] = r1[2];
        r1[0] = r2[0]; r1[1] = r2[1]; r1[2] = r2[2];
        if (h + 2 < Hn) { r2[0] = LDV(h + 2, w - 1); r2[1] = LDV(h + 2, w); r2[2] = LDV(h + 2, w + 1); }
        else { r2[0] = r2[1] = r2[2] = 0.f; }
    }
    #undef LDV
}

// ---------- kernel 3: projection GEMM via MFMA bf16 ----------
__global__ __launch_bounds__(256) void k_proj(const unsigned short* __restrict__ xcB,
                                              const float* __restrict__ xpw,
                                              float* __restrict__ P) {
    __shared__ short sA[64][40];
    __shared__ short sW[160][40];
    int r0 = blockIdx.x * 64;
    int tid = threadIdx.x;
    int w = tid >> 6, lane = tid & 63;
    int ln15 = lane & 15, q8 = (lane >> 4) * 8;
    f32x4 acc[10];
    #pragma unroll
    for (int i = 0; i < 10; ++i) acc[i] = f32x4{0.f, 0.f, 0.f, 0.f};
    for (int kk = 0; kk < 8; ++kk) {
        {
            int r = tid >> 2, c0 = (tid & 3) * 8;
            *(bf16x8*)&sA[r][c0] =
                *(const bf16x8*)(xcB + (size_t)(r0 + r) * DI + kk * 32 + c0);
        }
        if (tid < 160) {
            const float* src = xpw + (size_t)tid * DI + kk * 32;
            #pragma unroll
            for (int j = 0; j < 8; ++j) {
                float4 v = *(const float4*)(src + j * 4);
                sW[tid][j * 4 + 0] = (short)f2bf(v.x);
                sW[tid][j * 4 + 1] = (short)f2bf(v.y);
                sW[tid][j * 4 + 2] = (short)f2bf(v.z);
                sW[tid][j * 4 + 3] = (short)f2bf(v.w);
            }
        }
        __syncthreads();
        bf16x8 a = *(bf16x8*)&sA[w * 16 + ln15][q8];
        #pragma unroll
        for (int ni = 0; ni < 10; ++ni) {
            bf16x8 bfr = *(bf16x8*)&sW[ni * 16 + ln15][q8];
            acc[ni] = __builtin_amdgcn_mfma_f32_16x16x32_bf16(a, bfr, acc[ni], 0, 0, 0);
        }
        __syncthreads();
    }
    int rbase = r0 + w * 16 + (lane >> 4) * 4;
    #pragma unroll
    for (int ni = 0; ni < 10; ++ni)
        #pragma unroll
        for (int r = 0; r < 4; ++r)
            P[(size_t)(rbase + r) * 160 + ni * 16 + ln15] = acc[ni][r];
}

// ---------- scan step cores ----------
template <bool CHAIN>
__device__ __forceinline__ float s1_step(const float* __restrict__ rec, float u,
                                         const float wr[8], float bias, float Dv,
                                         const float* __restrict__ A_logs, int kd,
                                         float h[16], float& sde) {
    float dtv = bias + dot8(wr, rec);
    float de, e1;
    softplus_e1(dtv, de, e1);
    float du = de * u;
    sde += de;
    float Ba[16], Ca[16];
    #pragma unroll
    for (int i = 0; i < 4; ++i) {
        float4 v = *(const float4*)(rec + 8 + i * 4);
        Ba[i * 4 + 0] = v.x; Ba[i * 4 + 1] = v.y; Ba[i * 4 + 2] = v.z; Ba[i * 4 + 3] = v.w;
        float4 w = *(const float4*)(rec + 24 + i * 4);
        Ca[i * 4 + 0] = w.x; Ca[i * 4 + 1] = w.y; Ca[i * 4 + 2] = w.z; Ca[i * 4 + 3] = w.w;
    }
    float yv[4];
    yv[0] = Dv * u; yv[1] = 0.f; yv[2] = 0.f; yv[3] = 0.f;
    if constexpr (CHAIN) {
        float en[16];
        pow16(e1, en);
        #pragma unroll
        for (int n = 0; n < 16; ++n) {
            h[n] = en[n] * h[n] + du * Ba[n];
            yv[n & 3] += h[n] * Ca[n];
        }
    } else {
        #pragma unroll
        for (int n = 0; n < 16; ++n) {
            float Ac = -__expf(A_logs[(size_t)kd * 16 + n]);
            h[n] = __expf(de * Ac) * h[n] + du * Ba[n];
            yv[n & 3] += h[n] * Ca[n];
        }
    }
    return (yv[0] + yv[1]) + (yv[2] + yv[3]);
}
// correction: g[n] = h0[n]*pe^(n+1) maintained incrementally; returns sum g*C
template <bool CHAIN>
__device__ __forceinline__ float s3_step(const float* __restrict__ rec,
                                         const float wr[8], float bias,
                                         const float* __restrict__ A_logs, int kd,
                                         float g[16], const float h0[16], float& sde) {
    float dtv = bias + dot8(wr, rec);
    float Ca[16];
    #pragma unroll
    for (int i = 0; i < 4; ++i) {
        float4 w = *(const float4*)(rec + 24 + i * 4);
        Ca[i * 4 + 0] = w.x; Ca[i * 4 + 1] = w.y; Ca[i * 4 + 2] = w.z; Ca[i * 4 + 3] = w.w;
    }
    float cv[4] = {0.f, 0.f, 0.f, 0.f};
    if constexpr (CHAIN) {
        float E = __expf(dtv);
        float e1 = __builtin_amdgcn_rcpf(1.f + E);
        float en[16];
        pow16(e1, en);
        #pragma unroll
        for (int n = 0; n < 16; ++n) {
            g[n] *= en[n];
            cv[n & 3] += g[n] * Ca[n];
        }
    } else {
        float de = softplus_f(dtv);
        sde += de;
        #pragma unroll
        for (int n = 0; n < 16; ++n) {
            float Ac = -__expf(A_logs[(size_t)kd * 16 + n]);
            cv[n & 3] += Ca[n] * __expf(Ac * sde) * h0[n];
        }
    }
    return (cv[0] + cv[1]) + (cv[2] + cv[3]);
}

// ---------- kernel 4: paired local scan — R11 structure, occupancy 5 blocks/CU ----------
// grid 1024 = 4b * 2pair * 128c ; pair0 = dirs {0,2} -> y0(=d_out), pair1 = {1,3} -> y1 (wh-scan)
__global__ __launch_bounds__(256, 5) void k_scan1p(const unsigned short* __restrict__ xcB,
                                                   const float* __restrict__ P,
                                                   const float* __restrict__ dtw,
                                                   const float* __restrict__ dtb,
                                                   const float* __restrict__ A_logs,
                                                   const float* __restrict__ Ds,
                                                   float* __restrict__ carrG,
                                                   unsigned short* __restrict__ carrH,
                                                   float* __restrict__ y0,
                                                   float* __restrict__ y1) {
    __shared__ float sY[CHUNK * 256];   // per-thread-private column scratch
    int bid = blockIdx.x;
    int c = bid & (NC - 1);
    int p = (bid >> 7) & 1;
    int b = bid >> 8;
    int tid = threadIdx.x;
    int kA = p, kB = p + 2, cB = NC - 1 - c;
    int kdA = kA * DI + tid, kdB = kB * DI + tid;
    float wrA[8], wrB[8];
    load_wr(dtw, kdA, wrA);
    load_wr(dtw, kdB, wrB);
    float biasA = dtb[kdA], biasB = dtb[kdB];
    float DvA = Ds[kdA], DvB = Ds[kdB];
    bool ch = check_chain(A_logs, kdA) && check_chain(A_logs, kdB);
    float hA[16], hB[16];
    #pragma unroll
    for (int n = 0; n < 16; ++n) { hA[n] = 0.f; hB[n] = 0.f; }
    float sdeA = 0.f, sdeB = 0.f;
    for (int j = 0; j < CHUNK; ++j) sY[j * 256 + tid] = 0.f;
    // affine geometry within chunk
    int t0A = c * CHUNK, t0B = cB * CHUNK;
    int pA0 = posk(kA, t0A), dpA = posk(kA, t0A + 1) - pA0;
    int pB0 = posk(kB, t0B), dpB = posk(kB, t0B + 1) - pB0;
    const float* recA = P + ((size_t)b * LL + pA0) * 160 + kA * 40;
    const float* recB = P + ((size_t)b * LL + pB0) * 160 + kB * 40;
    const unsigned short* upA = xcB + ((size_t)b * LL + pA0) * DI + tid;
    const unsigned short* upB = xcB + ((size_t)b * LL + pB0) * DI + tid;
    long rsA = (long)dpA * 160, rsB = (long)dpB * 160;
    long usA = (long)dpA * DI, usB = (long)dpB * DI;
    if (ch) {
        for (int tt = 0; tt < CHUNK; ++tt) {
            float yvA = s1_step<true>(recA, bf2f(*upA), wrA, biasA, DvA, A_logs, kdA, hA, sdeA);
            float yvB = s1_step<true>(recB, bf2f(*upB), wrB, biasB, DvB, A_logs, kdB, hB, sdeB);
            recA += rsA; recB += rsB; upA += usA; upB += usB;
            sY[tt * 256 + tid] += yvA;
            sY[(CHUNK - 1 - tt) * 256 + tid] += yvB;
        }
    } else {
        for (int tt = 0; tt < CHUNK; ++tt) {
            float yvA = s1_step<false>(recA, bf2f(*upA), wrA, biasA, DvA, A_logs, kdA, hA, sdeA);
            float yvB = s1_step<false>(recB, bf2f(*upB), wrB, biasB, DvB, A_logs, kdB, hB, sdeB);
            recA += rsA; recB += rsB; upA += usA; upB += usB;
            sY[tt * 256 + tid] += yvA;
            sY[(CHUNK - 1 - tt) * 256 + tid] += yvB;
        }
    }
    // carries
    carrG[((size_t)(b * Kn + kA) * NC + c) * DI + tid] = sdeA;
    carrG[((size_t)(b * Kn + kB) * NC + cB) * DI + tid] = sdeB;
    size_t hbA = ((size_t)(b * Kn + kA) * NC + c) * 16 * DI + tid;
    size_t hbB = ((size_t)(b * Kn + kB) * NC + cB) * 16 * DI + tid;
    #pragma unroll
    for (int n = 0; n < 16; ++n) {
        carrH[hbA + (size_t)n * DI] = f2bf(hA[n]);
        carrH[hbB + (size_t)n * DI] = f2bf(hB[n]);
    }
    // plain stores of the 32-position window (owner-exclusive)
    float* yb = (p == 0 ? y0 : y1) + ((size_t)b * LL + c * CHUNK) * DI + tid;
    for (int j = 0; j < CHUNK; ++j)
        yb[(size_t)j * DI] = sY[j * 256 + tid];
}

// ---------- kernel 5: scan phase 2 — combine carries across chunks ----------
__global__ __launch_bounds__(256) void k_scan2(const float* __restrict__ carrG,
                                               const float* __restrict__ A_logs,
                                               unsigned short* __restrict__ carrH) {
    int gid = blockIdx.x * 256 + threadIdx.x;
    int d = gid & 255;
    int n = (gid >> 8) & 15;
    int bk = gid >> 12;
    int k = bk & 3;
    float Ac = -__expf(A_logs[(size_t)(k * DI + d) * 16 + n]);
    size_t gbase = (size_t)bk * NC * DI + d;
    size_t hbase = ((size_t)bk * NC * 16 + n) * DI + d;
    const size_t hs = (size_t)16 * DI;
    float hr = 0.f;
    #pragma unroll
    for (int g = 0; g < NC / 32; ++g) {
        float sv[32];
        unsigned short hvv[32];
        #pragma unroll
        for (int j = 0; j < 32; ++j) sv[j] = carrG[gbase + (size_t)(g * 32 + j) * DI];
        #pragma unroll
        for (int j = 0; j < 32; ++j) hvv[j] = carrH[hbase + (size_t)(g * 32 + j) * hs];
        #pragma unroll
        for (int j = 0; j < 32; ++j) {
            float a = __expf(Ac * sv[j]);
            float he = bf2f(hvv[j]);
            carrH[hbase + (size_t)(g * 32 + j) * hs] = f2bf(hr);
            hr = a * hr + he;
        }
    }
}

// ---------- kernel 6: paired correction — R11 structure, occupancy 5 blocks/CU ----------
__global__ __launch_bounds__(256, 5) void k_scan3p(const float* __restrict__ P,
                                                   const float* __restrict__ dtw,
                                                   const float* __restrict__ dtb,
                                                   const float* __restrict__ A_logs,
                                                   const unsigned short* __restrict__ carrH,
                                                   float* __restrict__ y0,
                                                   float* __restrict__ y1) {
    __shared__ float sY[CHUNK * 256];
    int bid = blockIdx.x;
    int c = bid & (NC - 1);
    int p = (bid >> 7) & 1;
    int b = bid >> 8;
    int tid = threadIdx.x;
    int kA = p, kB = p + 2, cB = NC - 1 - c;
    int kdA = kA * DI + tid, kdB = kB * DI + tid;
    float wrA[8], wrB[8];
    load_wr(dtw, kdA, wrA);
    load_wr(dtw, kdB, wrB);
    float biasA = dtb[kdA], biasB = dtb[kdB];
    bool ch = check_chain(A_logs, kdA) && check_chain(A_logs, kdB);
    float gA[16], h0A[16], gB[16], h0B[16];
    size_t hbA = ((size_t)(b * Kn + kA) * NC + c) * 16 * DI + tid;
    size_t hbB = ((size_t)(b * Kn + kB) * NC + cB) * 16 * DI + tid;
    #pragma unroll
    for (int n = 0; n < 16; ++n) {
        h0A[n] = bf2f(carrH[hbA + (size_t)n * DI]); gA[n] = h0A[n];
        h0B[n] = bf2f(carrH[hbB + (size_t)n * DI]); gB[n] = h0B[n];
    }
    for (int j = 0; j < CHUNK; ++j) sY[j * 256 + tid] = 0.f;
    int t0A = c * CHUNK, t0B = cB * CHUNK;
    int pA0 = posk(kA, t0A), dpA = posk(kA, t0A + 1) - pA0;
    int pB0 = posk(kB, t0B), dpB = posk(kB, t0B + 1) - pB0;
    const float* recA = P + ((size_t)b * LL + pA0) * 160 + kA * 40;
    const float* recB = P + ((size_t)b * LL + pB0) * 160 + kB * 40;
    long rsA = (long)dpA * 160, rsB = (long)dpB * 160;
    float sdeA = 0.f, sdeB = 0.f;
    if (ch) {
        for (int tt = 0; tt < CHUNK; ++tt) {
            float crA = s3_step<true>(recA, wrA, biasA, A_logs, kdA, gA, h0A, sdeA);
            float crB = s3_step<true>(recB, wrB, biasB, A_logs, kdB, gB, h0B, sdeB);
            recA += rsA; recB += rsB;
            sY[tt * 256 + tid] += crA;
            sY[(CHUNK - 1 - tt) * 256 + tid] += crB;
        }
    } else {
        for (int tt = 0; tt < CHUNK; ++tt) {
            float crA = s3_step<false>(recA, wrA, biasA, A_logs, kdA, gA, h0A, sdeA);
            float crB = s3_step<false>(recB, wrB, biasB, A_logs, kdB, gB, h0B, sdeB);
            recA += rsA; recB += rsB;
            sY[tt * 256 + tid] += crA;
            sY[(CHUNK - 1 - tt) * 256 + tid] += crB;
        }
    }
    float* yb = (p == 0 ? y0 : y1) + ((size_t)b * LL + c * CHUNK) * DI + tid;
    for (int j = 0; j < CHUNK; ++j)
        yb[(size_t)j * DI] += sY[j * 256 + tid];
}

// ---------- kernel 7: LayerNorm — one wave per row, float4, no LDS/barrier ----------
// grid 4096 = 16384 rows / 4 rows per block ; block 256 = 4 waves
__global__ __launch_bounds__(256) void k_ln(float* __restrict__ y,
                                            const float* __restrict__ y1,
                                            const float* __restrict__ gamma,
                                            const float* __restrict__ beta) {
    int tid = threadIdx.x;
    int w = tid >> 6, lane = tid & 63;
    int r = blockIdx.x * 4 + w;
    int b = r >> 12;
    int pos = r & 4095;
    int q = ((pos & 63) << 6) | (pos >> 6);   // y1 is stored in wh-scan order
    float4 vy = *(const float4*)(y + (size_t)r * DI + lane * 4);
    float4 vz = *(const float4*)(y1 + ((size_t)b * LL + q) * DI + lane * 4);
    float v0 = vy.x + vz.x, v1 = vy.y + vz.y, v2 = vy.z + vz.z, v3 = vy.w + vz.w;
    float a = (v0 + v1) + (v2 + v3);
    float bsq = (v0 * v0 + v1 * v1) + (v2 * v2 + v3 * v3);
    #pragma unroll
    for (int off = 32; off; off >>= 1) {
        a += __shfl_xor(a, off);
        bsq += __shfl_xor(bsq, off);
    }
    float mu = a * (1.f / 256.f);
    float var = bsq * (1.f / 256.f) - mu * mu;
    float rs = rsqrtf(var + 1e-5f);
    float4 gm = *(const float4*)(gamma + lane * 4);
    float4 bt = *(const float4*)(beta + lane * 4);
    float4 o;
    o.x = (v0 - mu) * rs * gm.x + bt.x;
    o.y = (v1 - mu) * rs * gm.y + bt.y;
    o.z = (v2 - mu) * rs * gm.z + bt.z;
    o.w = (v3 - mu) * rs * gm.w + bt.w;
    *(float4*)(y + (size_t)r * DI + lane * 4) = o;
}

// ---------- launch ----------
extern "C" void kernel_launch(void* const* d_in, const int* in_sizes, int n_in,
                              void* d_out, int out_size, void* d_ws, size_t ws_size,
                              hipStream_t stream) {
    const float* x    = (const float*)d_in[0];
    const float* ipw  = (const float*)d_in[1];
    const float* cw   = (const float*)d_in[2];
    const float* cb   = (const float*)d_in[3];
    const float* xpw  = (const float*)d_in[4];
    const float* dtw  = (const float*)d_in[5];
    const float* dtb  = (const float*)d_in[6];
    const float* alog = (const float*)d_in[7];
    const float* Ds   = (const float*)d_in[8];
    const float* gam  = (const float*)d_in[9];
    const float* bet  = (const float*)d_in[10];

    // ws layout (bytes):
    //   [0, 16777216)           carrH (bf16) -- aliases xls_pre (in_proj out, dead after conv)
    //   [16777216, 18874368)    carrG (fp32)
    //   [18874368, 27262976)    xcB   (bf16 B*L*DI)
    //   [27262976, 37748736)    P     (fp32 B*L*160, image order: [k*40: dts|B|C])
    //   [37748736, 54525952)    y1    (fp32 B*L*DI, pair{1,3} partial in wh-scan order)
    const size_t WS_NEED = 54525952;
    if (ws_size < WS_NEED) return;

    char* ws = (char*)d_ws;
    unsigned short* carrH = (unsigned short*)(ws + 0);
    float* carrG   = (float*)(ws + 16777216);
    float* xls_pre = (float*)(ws + 0);
    unsigned short* xcB = (unsigned short*)(ws + 18874368);
    float* P       = (float*)(ws + 27262976);
    float* y1      = (float*)(ws + 37748736);
    float* y       = (float*)d_out;

    k_inproj<<<256,   256, 0, stream>>>(x, ipw, xls_pre);
    k_conv  <<<512,   256, 0, stream>>>(xls_pre, cw, cb, xcB);
    k_proj  <<<256,   256, 0, stream>>>(xcB, xpw, P);
    k_scan1p<<<1024,  256, 0, stream>>>(xcB, P, dtw, dtb, alog, Ds, carrG, carrH, y, y1);
    k_scan2 <<<256,   256, 0, stream>>>(carrG, alog, carrH);
    k_scan3p<<<1024,  256, 0, stream>>>(P, dtw, dtb, alog, carrH, y, y1);
    k_ln    <<<4096,  256, 0, stream>>>(y, y1, gam, bet);
}